// Round 11
// baseline (1102.003 us; speedup 1.0000x reference)
//
#include <hip/hip_runtime.h>
#include <hip/hip_fp16.h>
#include <math.h>

// ---------------- problem constants ----------------
namespace {
constexpr int kB   = 4;
constexpr int kNG  = 100;
constexpr int kH1  = 112;            // feat H/W
constexpr int kH2  = 224;            // upscaled H/W
constexpr int kQ   = kH2 * kH2;      // 50176 queries per batch image
constexpr int kP1  = kH1 * kH1;      // 12544 pixels per image (feat res)

// workspace layout (bytes).
constexpr size_t OFF_FBH  = 0;                       // bf16 feat hi [4*12544][64] = 6,422,528
constexpr size_t OFF_FBL  = 6422528;                 // bf16 feat lo
constexpr size_t OFF_GFH  = 0;                       // bf16 gfeat hi [224*224][64] (overlaps fb)
constexpr size_t OFF_GFL  = 6422528;                 // bf16 gfeat lo
constexpr size_t OFF_H    = 12845056;                // fp32 h [4*12544][64] = 12,845,056
constexpr size_t OFF_CF   = 25690112;                // fp16 cf [224*224][512] = 51,380,224
constexpr size_t OFF_WPH  = OFF_CF + 51380224;       // conv2 W frag-order hi, 589,824
constexpr size_t OFF_WPL  = OFF_WPH + 589824;        // conv2 W frag-order lo
constexpr size_t OFF_W1H  = OFF_WPL + 589824;        // conv1 W frag-order hi, 73,728
constexpr size_t OFF_W1L  = OFF_W1H + 73728;
constexpr size_t OFF_WMLP = OFF_W1L + 73728;         // mlp W1/W2 frag-order hi/lo, 524,288
constexpr size_t OFF_WSUM = OFF_WMLP + 524288;
constexpr size_t OFF_WK   = OFF_WSUM + 1024;
// total ~79 MB
}  // namespace

using s8v = __attribute__((ext_vector_type(8))) short;   // 8 bf16 (4 VGPRs)
using f4v = __attribute__((ext_vector_type(4))) float;   // MFMA acc
using u4v = __attribute__((ext_vector_type(4))) unsigned int;  // native vec for nt-store

__device__ __forceinline__ unsigned short f2bf(float f) {
  unsigned int u = __float_as_uint(f);
  unsigned int r = u + 0x7fffu + ((u >> 16) & 1u);   // round-nearest-even
  return (unsigned short)(r >> 16);
}
__device__ __forceinline__ float bf2f(unsigned short h) {
  return __uint_as_float((unsigned int)h << 16);
}
__device__ __forceinline__ unsigned short f2h(float f) {
  return __builtin_bit_cast(unsigned short, __float2half(f));  // RNE
}
__device__ __forceinline__ float h2f(unsigned short u) {
  return __half2float(__builtin_bit_cast(__half, u));
}

// ---------------- tiny helpers ----------------
__global__ void k_init(float* wsums) {
  int t = threadIdx.x;
  if (t < 196) wsums[t] = 0.0f;
}

// feat fp32 channel-major -> pixel-major bf16 hi/lo (LDS transpose, coalesced both sides)
__global__ __launch_bounds__(256) void k_prepfeat(const float* __restrict__ feat,
                                                  unsigned short* __restrict__ fbh,
                                                  unsigned short* __restrict__ fbl) {
  __shared__ float ls[64 * 65];
  const int t = threadIdx.x;
  const int b = blockIdx.x / 196;       // image
  const int seg = blockIdx.x % 196;     // 64-pixel segment within image
  const int pixbase = seg * 64;
  for (int idx = t; idx < 4096; idx += 256) {
    int ci = idx >> 6, px = idx & 63;
    ls[px * 65 + ci] = feat[((size_t)(b * 64 + ci)) * kP1 + pixbase + px];
  }
  __syncthreads();
  for (int idx = t; idx < 4096; idx += 256) {
    int px = idx >> 6, ci = idx & 63;
    float v = ls[px * 65 + ci];
    unsigned short hi = f2bf(v);
    unsigned short lo = f2bf(v - bf2f(hi));
    size_t o = ((size_t)(b * kP1 + pixbase + px)) * 64 + ci;
    fbh[o] = hi;
    fbl[o] = lo;
  }
}

// Pack conv2 weights into MFMA B-fragment order, split bf16 hi/lo.
__global__ void k_prepw(const float* __restrict__ cw, const float* __restrict__ fw,
                        unsigned short* __restrict__ wph, unsigned short* __restrict__ wpl) {
  int e = blockIdx.x * 256 + threadIdx.x;   // 512*576 = 294912
  int co = e / 576, k = e % 576;
  int ci = k & 63, kk = k >> 6;
  float v = (co < 256) ? cw[co * 576 + ci * 9 + kk] : fw[(co - 256) * 576 + ci * 9 + kk];
  unsigned short hi = f2bf(v);
  unsigned short lo = f2bf(v - bf2f(hi));
  int n16 = co >> 4, nl = co & 15;
  int kstep = k >> 5, kr = k & 31;
  int dst = ((n16 * 18 + kstep) * 64 + (kr >> 3) * 16 + nl) * 8 + (kr & 7);
  wph[dst] = hi;
  wpl[dst] = lo;
}

// Pack conv1 weights (64 co) into the same B-frag order.
__global__ void k_prepw1(const float* __restrict__ w1src,
                         unsigned short* __restrict__ wph, unsigned short* __restrict__ wpl) {
  int e = blockIdx.x * 256 + threadIdx.x;   // 64*576 = 36864
  int co = e / 576, k = e % 576;
  int ci = k & 63, kk = k >> 6;
  float v = w1src[co * 576 + ci * 9 + kk];
  unsigned short hi = f2bf(v);
  unsigned short lo = f2bf(v - bf2f(hi));
  int n16 = co >> 4, nl = co & 15;
  int kstep = k >> 5, kr = k & 31;
  int dst = ((n16 * 18 + kstep) * 64 + (kr >> 3) * 16 + nl) * 8 + (kr & 7);
  wph[dst] = hi;
  wpl[dst] = lo;
}

// Pack MLP W1/W2 into B-frag order hi/lo. wmlp layout: [mat][hi/lo][65536 bf16]
__global__ void k_prepmlp(const float* __restrict__ w1, const float* __restrict__ w2,
                          unsigned short* __restrict__ wp) {
  int e = blockIdx.x * 256 + threadIdx.x;   // 131072
  int mat = e >> 16, idx = e & 65535;
  int j = idx >> 8, k = idx & 255;
  float v = (mat ? w2 : w1)[j * 256 + k];
  unsigned short hi = f2bf(v);
  unsigned short lo = f2bf(v - bf2f(hi));
  int n16 = j >> 4, nl = j & 15;
  int kstep = k >> 5, kr = k & 31;
  int dst = ((n16 * 8 + kstep) * 64 + (kr >> 3) * 16 + nl) * 8 + (kr & 7);
  wp[mat * 131072 + dst] = hi;
  wp[mat * 131072 + 65536 + dst] = lo;
}

// ---------------- conv1 as bf16x3 MFMA implicit GEMM, ReLU, pixel-major fp32 out ----------------
__global__ __launch_bounds__(256) void k_conv1_mfma(
    const unsigned short* __restrict__ fbh, const unsigned short* __restrict__ fbl,
    const unsigned short* __restrict__ wph, const unsigned short* __restrict__ wpl,
    const float* __restrict__ bias, float* __restrict__ outp) {  // h [4*12544][64]
  __shared__ __attribute__((aligned(16))) char Asb[2 * 180 * 144];  // 51,840 B
  const int t = threadIdx.x;
  const int blk = blockIdx.x;          // 4 b * 7 ty * 14 tx = 392
  const int b = blk / 98;
  const int mt = blk % 98;
  const int ty = mt / 14, tx = mt % 14;
  const int py0 = ty * 16, px0 = tx * 8;

  for (int idx = t; idx < 2880; idx += 256) {
    int plane = idx >= 1440;
    int r2 = plane ? idx - 1440 : idx;
    int p = r2 >> 3, c8 = r2 & 7;
    int pr = p / 10, pc = p % 10;
    int gy = py0 - 1 + pr, gx = px0 - 1 + pc;
    uint4 u = make_uint4(0u, 0u, 0u, 0u);
    if (gy >= 0 && gy < kH1 && gx >= 0 && gx < kH1) {
      const unsigned short* src = (plane ? fbl : fbh) +
          ((size_t)(b * kP1 + gy * kH1 + gx)) * 64 + c8 * 8;
      u = *(const uint4*)src;
    }
    *(uint4*)(Asb + plane * 25920 + p * 144 + c8 * 16) = u;
  }
  __syncthreads();

  const int w = t >> 6, lane = t & 63;
  const int quad = lane >> 4, ml = lane & 15;
  const unsigned int bvoff = (unsigned int)lane * 16u;

  f4v acc[8];
#pragma unroll
  for (int i = 0; i < 8; ++i) acc[i] = (f4v){0.0f, 0.0f, 0.0f, 0.0f};

#pragma unroll
  for (int kk = 0; kk < 9; ++kk) {
    const int ky = kk / 3, kx = kk % 3;
#pragma unroll
    for (int cs = 0; cs < 2; ++cs) {
      const int kstep = kk * 2 + cs;
      unsigned int off = ((unsigned int)(w * 18 + kstep)) * 1024u + bvoff;
      s8v Bh = *(const s8v*)((const char*)wph + off);
      s8v Bl = *(const s8v*)((const char*)wpl + off);
#pragma unroll
      for (int i = 0; i < 8; ++i) {
        const int aoff = ((2 * i + (ml >> 3) + ky) * 10 + (ml & 7) + kx) * 144 + cs * 64 + quad * 16;
        s8v Ah = *(const s8v*)(Asb + aoff);
        s8v Al = *(const s8v*)(Asb + 25920 + aoff);
        acc[i] = __builtin_amdgcn_mfma_f32_16x16x32_bf16(Ah, Bh, acc[i], 0, 0, 0);
        acc[i] = __builtin_amdgcn_mfma_f32_16x16x32_bf16(Al, Bh, acc[i], 0, 0, 0);
        acc[i] = __builtin_amdgcn_mfma_f32_16x16x32_bf16(Ah, Bl, acc[i], 0, 0, 0);
      }
    }
  }

  const float bv = bias[w * 16 + ml];
#pragma unroll
  for (int i = 0; i < 8; ++i)
#pragma unroll
    for (int reg = 0; reg < 4; ++reg) {
      int m = i * 16 + quad * 4 + reg;
      int Y = py0 + (m >> 3), X = px0 + (m & 7);
      outp[((size_t)(b * kP1 + Y * kH1 + X)) * 64 + w * 16 + ml] =
          fmaxf(acc[i][reg] + bv, 0.0f);
    }
}

// ---------------- 1x1 conv + softmax + weighted sums -> wsums[4][49] ----------------
__global__ __launch_bounds__(256) void k_wavg(
    const float* __restrict__ h, const float* __restrict__ w2, const float* __restrict__ b2,
    const float* __restrict__ sx, const float* __restrict__ sy,
    const float* __restrict__ op, const float* __restrict__ rho,
    float* __restrict__ wsums) {
  __shared__ float w2s[kNG * 64];
  __shared__ float prm[4 * kNG];
  __shared__ float b2s[kNG];
  __shared__ float pl[196];
  const int t = threadIdx.x;
  for (int i = t; i < kNG * 64; i += 256) w2s[i] = w2[i];
  if (t < kNG) {
    prm[t] = sx[t];
    prm[kNG + t] = sy[t];
    prm[2 * kNG + t] = op[t];
    prm[3 * kNG + t] = rho[t];
    b2s[t] = b2[t];
  }
  if (t < 196) pl[t] = 0.0f;
  __syncthreads();
  const int id = blockIdx.x * 256 + t;
  float hreg[64];
  const float4* hp = (const float4*)(h + (size_t)id * 64);
#pragma unroll
  for (int i = 0; i < 16; ++i) {
    float4 v = hp[i];
    hreg[4 * i] = v.x; hreg[4 * i + 1] = v.y;
    hreg[4 * i + 2] = v.z; hreg[4 * i + 3] = v.w;
  }
  float S = 0, Sx = 0, Sy = 0, So = 0, Sr = 0;
  for (int g = 0; g < kNG; ++g) {
    float d = b2s[g];
    const float4* wp = (const float4*)(w2s + g * 64);
#pragma unroll
    for (int i = 0; i < 16; ++i) {
      float4 w = wp[i];
      d += hreg[4 * i] * w.x + hreg[4 * i + 1] * w.y +
           hreg[4 * i + 2] * w.z + hreg[4 * i + 3] * w.w;
    }
    float e = expf(d);
    S += e;
    Sx += e * prm[g];
    Sy += e * prm[kNG + g];
    So += e * prm[2 * kNG + g];
    Sr += e * prm[3 * kNG + g];
  }
  const int rem = id % (kH1 * kH1);
  const int p = ((rem / kH1) % 7) * 7 + ((rem % kH1) % 7);
  const float inv = 1.0f / S;
  atomicAdd(&pl[p], Sx * inv);
  atomicAdd(&pl[49 + p], Sy * inv);
  atomicAdd(&pl[98 + p], So * inv);
  atomicAdd(&pl[147 + p], Sr * inv);
  __syncthreads();
  if (t < 196) atomicAdd(&wsums[t], pl[t]);
}

// ---------------- build wk[p][h][w] ----------------
__global__ __launch_bounds__(256) void k_finalize(const float* __restrict__ wsums,
                                                  float* __restrict__ wk) {
  __shared__ float kern_s[49 * 25];
  __shared__ float wavg_s[196];
  const int t = threadIdx.x;
  if (t < 196) wavg_s[t] = wsums[t] * (1.0f / 1024.0f);
  __syncthreads();
  if (t < 49) {
    float wsx = wavg_s[t], wsy = wavg_s[49 + t], wr = wavg_s[147 + t];
    float c00 = wsx * wsx + 1e-5f;
    float c11 = wsy * wsy + 1e-5f;
    float c01 = wr * wsx * wsy;
    float det = c00 * c11 - c01 * c01;
    float i00 = c11 / det, i11 = c00 / det, i01 = -c01 / det;
    float nrm = 1.0f / (2.0f * 3.14159265358979323846f * sqrtf(det));
    float vals[25];
    float mx = -1e30f;
#pragma unroll
    for (int i = 0; i < 5; ++i) {
#pragma unroll
      for (int j = 0; j < 5; ++j) {
        float yv = -5.0f + 2.5f * (float)i;
        float xv = -5.0f + 2.5f * (float)j;
        float z = -0.5f * (i00 * xv * xv + 2.0f * i01 * xv * yv + i11 * yv * yv);
        float v = expf(z) * nrm;
        vals[i * 5 + j] = v;
        mx = fmaxf(mx, v);
      }
    }
#pragma unroll
    for (int k = 0; k < 25; ++k) kern_s[t * 25 + k] = vals[k] / mx;
  }
  __syncthreads();
  for (int idx = t; idx < 49 * 196; idx += 256) {
    const int p = idx / 196;
    const int hw = idx % 196;
    const int hh = hw / 14, ww = hw % 14;
    float txv = (0.5f - (float)(p / 7) / 7.0f) * 2.0f;
    float tyv = (0.5f - (float)(p % 7) / 7.0f) * 2.0f;
    float gxv = (-1.0f + (float)ww * (2.0f / 13.0f)) + txv;
    float gyv = (-1.0f + (float)hh * (2.0f / 13.0f)) + tyv;
    float pxv = (gxv + 1.0f) * 0.5f * 13.0f;
    float pyv = (gyv + 1.0f) * 0.5f * 13.0f;
    float x0f = floorf(pxv), y0f = floorf(pyv);
    int x0 = (int)x0f, y0 = (int)y0f;
    float wx = pxv - x0f, wy = pyv - y0f;
    auto samp = [&](int yi, int xi) -> float {
      if (yi < 4 || yi >= 9 || xi < 4 || xi >= 9) return 0.0f;
      return kern_s[p * 25 + (yi - 4) * 5 + (xi - 4)];
    };
    float kt = samp(y0, x0) * (1.0f - wy) * (1.0f - wx) +
               samp(y0, x0 + 1) * (1.0f - wy) * wx +
               samp(y0 + 1, x0) * wy * (1.0f - wx) +
               samp(y0 + 1, x0 + 1) * wy * wx;
    wk[idx] = wavg_s[98 + p] * kt;
  }
}

// ---------------- splat (ONE image) -> pixel-major bf16 hi/lo gfeat ----------------
__global__ __launch_bounds__(256) void k_splat(const float* __restrict__ feat,
                                               const float* __restrict__ wk,
                                               unsigned short* __restrict__ gfh,
                                               unsigned short* __restrict__ gfl) {
  __shared__ float fs[64 * 49];
  __shared__ float wks[49 * 196];
  const int t = threadIdx.x;
  const int rem = blockIdx.x;   // 256 tiles
  const int ry = rem >> 4, rx = rem & 15;
  for (int idx = t; idx < 64 * 49; idx += 256) {
    int ci = idx / 49, p = idx % 49;
    int gy = ry * 7 + p / 7, gx = rx * 7 + p % 7;
    fs[idx] = feat[((size_t)ci * kH1 + gy) * kH1 + gx];
  }
  for (int idx = t; idx < 49 * 196; idx += 256) wks[idx] = wk[idx];
  __syncthreads();
  const int ci = t & 63;
  const int s = t >> 6;
  const int h0 = (s >> 1) * 7, w0 = (s & 1) * 7;
  float acc[49];
#pragma unroll
  for (int i = 0; i < 49; ++i) acc[i] = 0.0f;
  for (int p = 0; p < 49; ++p) {
    float f = fs[ci * 49 + p];
#pragma unroll
    for (int i = 0; i < 7; ++i)
#pragma unroll
      for (int j = 0; j < 7; ++j)
        acc[i * 7 + j] += f * wks[p * 196 + (h0 + i) * 14 + (w0 + j)];
  }
#pragma unroll
  for (int i = 0; i < 7; ++i)
#pragma unroll
    for (int j = 0; j < 7; ++j) {
      int Y = ry * 14 + h0 + i;
      int X = rx * 14 + w0 + j;
      float v = fminf(fmaxf(acc[i * 7 + j], 0.0f), 1.0f);
      unsigned short hi = f2bf(v);
      unsigned short lo = f2bf(v - bf2f(hi));
      size_t o = ((size_t)Y * kH2 + X) * 64 + ci;
      gfh[o] = hi;
      gfl[o] = lo;
    }
}

// ---------------- conv2 as bf16x3 MFMA implicit GEMM (ONE image), fp16 output ----------------
// Round 11: M=64 wave tile (acc[4][4] = 64 VGPR) + __launch_bounds__(256,3)
// (cap 170 VGPR; live state ~150, spill-safe margin). Round-10 counters:
// VGPR=256 -> 8 waves/CU, MfmaUtil 27%, hbm 1.27 TB/s -> latency-bound.
// 3 waves/SIMD + 2x more blocks should lift MfmaUtil and shrink the tail.
__global__ __launch_bounds__(256, 3) void k_conv2_mfma(
    const unsigned short* __restrict__ gfh, const unsigned short* __restrict__ gfl,
    const unsigned short* __restrict__ wph, const unsigned short* __restrict__ wpl,
    const float* __restrict__ coef_b, const float* __restrict__ freq_b,
    unsigned short* __restrict__ outp) {     // fp16 [224*224][512]
  __shared__ __attribute__((aligned(16))) char Asb[2 * 100 * 144];  // 28,800 B
  const int t = threadIdx.x;
  const int blk = blockIdx.x;       // 784 Mtiles * 2 Nhalves = 1568
  const int nb = blk & 1;
  const int mt = blk >> 1;
  const int ty = mt / 28, tx = mt % 28;
  const int py0 = ty * 8, px0 = tx * 8;

  // stage 10x10 halo (hi+lo planes)
  for (int idx = t; idx < 1600; idx += 256) {
    int plane = idx >= 800;
    int r2 = plane ? idx - 800 : idx;
    int p = r2 >> 3, c8 = r2 & 7;
    int pr = p / 10, pc = p % 10;
    int gy = py0 - 1 + pr, gx = px0 - 1 + pc;
    uint4 u = make_uint4(0u, 0u, 0u, 0u);
    if (gy >= 0 && gy < kH2 && gx >= 0 && gx < kH2) {
      const unsigned short* src = (plane ? gfl : gfh) + ((size_t)(gy * kH2 + gx)) * 64 + c8 * 8;
      u = *(const uint4*)src;
    }
    *(uint4*)(Asb + plane * 14400 + p * 144 + c8 * 16) = u;
  }
  __syncthreads();

  const int w = t >> 6, lane = t & 63;
  const int quad = lane >> 4, ml = lane & 15;
  const int n16base = nb * 16 + w * 4;
  const unsigned int bvoff = (unsigned int)lane * 16u;

  f4v acc[4][4];
#pragma unroll
  for (int i = 0; i < 4; ++i)
#pragma unroll
    for (int j = 0; j < 4; ++j) acc[i][j] = (f4v){0.0f, 0.0f, 0.0f, 0.0f};

#pragma unroll
  for (int kk = 0; kk < 9; ++kk) {
    const int ky = kk / 3, kx = kk % 3;
#pragma unroll
    for (int cs = 0; cs < 2; ++cs) {
      const int kstep = kk * 2 + cs;
      s8v Bh[4], Bl[4];
#pragma unroll
      for (int j = 0; j < 4; ++j) {
        unsigned int off = ((unsigned int)(n16base + j) * 18u + (unsigned int)kstep) * 1024u + bvoff;
        Bh[j] = *(const s8v*)((const char*)wph + off);
        Bl[j] = *(const s8v*)((const char*)wpl + off);
      }
#pragma unroll
      for (int i = 0; i < 4; ++i) {
        const int aoff = ((2 * i + (ml >> 3) + ky) * 10 + (ml & 7) + kx) * 144 + cs * 64 + quad * 16;
        s8v Ah = *(const s8v*)(Asb + aoff);
        s8v Al = *(const s8v*)(Asb + 14400 + aoff);
#pragma unroll
        for (int j = 0; j < 4; ++j) {
          acc[i][j] = __builtin_amdgcn_mfma_f32_16x16x32_bf16(Ah, Bh[j], acc[i][j], 0, 0, 0);
          acc[i][j] = __builtin_amdgcn_mfma_f32_16x16x32_bf16(Al, Bh[j], acc[i][j], 0, 0, 0);
          acc[i][j] = __builtin_amdgcn_mfma_f32_16x16x32_bf16(Ah, Bl[j], acc[i][j], 0, 0, 0);
        }
      }
    }
  }

  // ---- epilogue via LDS (16-pixel chunks), fp16 nt full-line stores ----
  const int cobase = nb * 256 + w * 64;
  float bj[4];
#pragma unroll
  for (int j = 0; j < 4; ++j) {
    int co = cobase + j * 16 + ml;
    bj[j] = (co < 256) ? coef_b[co] : freq_b[co - 256];
  }
  __syncthreads();               // Asb (A-tile) dead; reuse as staging
  float* Ls = (float*)Asb;       // [16 pixels][268 floats] = 17,152 B
  const int pq = t >> 4;         // pixel slot 0..15 for the read phase
  const int ts = t & 15;         // 16 threads per pixel
#pragma unroll
  for (int i = 0; i < 4; ++i) {
#pragma unroll
    for (int j = 0; j < 4; ++j)
#pragma unroll
      for (int reg = 0; reg < 4; ++reg) {
        const int p = quad * 4 + reg;                       // 0..15
        Ls[p * 268 + w * 64 + j * 16 + ml] = acc[i][j][reg] + bj[j];
      }
    __syncthreads();
    const int m = i * 16 + pq;                              // pixel in M-tile
    const int Y = py0 + (m >> 3), X = px0 + (m & 7);
    unsigned short* orow = outp + ((size_t)(Y * kH2 + X)) * 512 + nb * 256;
    const float* lrow = Ls + pq * 268;
#pragma unroll
    for (int u = 0; u < 2; ++u) {
      float4 a = *(const float4*)(lrow + ts * 16 + u * 8);
      float4 b = *(const float4*)(lrow + ts * 16 + u * 8 + 4);
      u4v v;
      v.x = (unsigned)f2h(a.x) | ((unsigned)f2h(a.y) << 16);
      v.y = (unsigned)f2h(a.z) | ((unsigned)f2h(a.w) << 16);
      v.z = (unsigned)f2h(b.x) | ((unsigned)f2h(b.y) << 16);
      v.w = (unsigned)f2h(b.z) | ((unsigned)f2h(b.w) << 16);
      __builtin_nontemporal_store(v, (u4v*)(orow + ts * 16 + u * 8));
    }
    __syncthreads();
  }
}

// ---------------- fused query (ONE image): fp16 gather + basis + bf16x3 MFMA MLP ----------------
__global__ __launch_bounds__(256, 2) void k_query_mfma(
    const unsigned short* __restrict__ cfh,    // fp16 cf
    const float* __restrict__ coord,
    const float* __restrict__ cell, const float* __restrict__ phw,
    const unsigned short* __restrict__ wmlp,   // [2][hi/lo][65536]
    const float* __restrict__ b1, const float* __restrict__ b2,
    const float* __restrict__ w3, const float* __restrict__ b3,
    float* __restrict__ out, int q_base) {
  __shared__ __attribute__((aligned(16))) char Xs[2 * 64 * 264 * 2];  // 67,584 B
  constexpr int ROW = 264 * 2;
  constexpr int PLANE = 64 * 264 * 2;
  const int t = threadIdx.x;
  const int q0 = q_base + blockIdx.x * 64;

  {
    const int tq = t >> 2, ts = t & 3;
    const int qg = q0 + tq;
    float gy = coord[(size_t)qg * 2 + 0];
    float gx = coord[(size_t)qg * 2 + 1];
    float fx = ((gx + 1.0f) * 224.0f - 1.0f) * 0.5f;
    float fy = ((gy + 1.0f) * 224.0f - 1.0f) * 0.5f;
    int ix = (int)rintf(fx);
    int iy = (int)rintf(fy);
    bool ok = (ix >= 0) && (ix < 224) && (iy >= 0) && (iy < 224);
    int ixc = min(max(ix, 0), 223);
    int iyc = min(max(iy, 0), 223);
    float m = ok ? 1.0f : 0.0f;
    float qcy = ok ? (-1.0f + (1.0f / 224.0f) + (2.0f / 224.0f) * (float)iyc) : 0.0f;
    float qcx = ok ? (-1.0f + (1.0f / 224.0f) + (2.0f / 224.0f) * (float)ixc) : 0.0f;
    float rel0 = (gy - qcy) * 224.0f;
    float rel1 = (gx - qcx) * 224.0f;
    float rc0 = cell[(size_t)qg * 2 + 0] * 224.0f;
    float rc1 = cell[(size_t)qg * 2 + 1] * 224.0f;
    const unsigned short* base = cfh + (((size_t)iyc * kH2 + ixc) * 512);
    unsigned short ch_[8], cl_[8], sh_[8], sl_[8];
#pragma unroll
    for (int u = 0; u < 8; ++u) {
      const int k4 = ts * 32 + u * 4;
      ushort4 clo = *(const ushort4*)(base + k4);
      ushort4 chi = *(const ushort4*)(base + 128 + k4);
      ushort4 f0 = *(const ushort4*)(base + 256 + 2 * k4);
      ushort4 f1 = *(const ushort4*)(base + 256 + 2 * k4 + 4);
      float fr[8] = {h2f(f0.x), h2f(f0.y), h2f(f0.z), h2f(f0.w),
                     h2f(f1.x), h2f(f1.y), h2f(f1.z), h2f(f1.w)};
      float cl4[4] = {h2f(clo.x), h2f(clo.y), h2f(clo.z), h2f(clo.w)};
      float ch4[4] = {h2f(chi.x), h2f(chi.y), h2f(chi.z), h2f(chi.w)};
#pragma unroll
      for (int e = 0; e < 4; ++e) {
        const int k = k4 + e;
        float ph = rc0 * phw[2 * k] + rc1 * phw[2 * k + 1];
        float s = m * (fr[2 * e] * rel0 + fr[2 * e + 1] * rel1) + ph;
        float sv, cv;
        sincospif(s, &sv, &cv);
        float xc = m * cl4[e] * cv;
        float xsn = m * ch4[e] * sv;
        const int sl = (u & 1) * 4 + e;
        unsigned short h1_ = f2bf(xc);
        ch_[sl] = h1_; cl_[sl] = f2bf(xc - bf2f(h1_));
        unsigned short h2_ = f2bf(xsn);
        sh_[sl] = h2_; sl_[sl] = f2bf(xsn - bf2f(h2_));
      }
      if (u & 1) {
        const int kb = ts * 32 + (u - 1) * 4;
        uint4 v;
        v.x = (unsigned)ch_[0] | ((unsigned)ch_[1] << 16);
        v.y = (unsigned)ch_[2] | ((unsigned)ch_[3] << 16);
        v.z = (unsigned)ch_[4] | ((unsigned)ch_[5] << 16);
        v.w = (unsigned)ch_[6] | ((unsigned)ch_[7] << 16);
        *(uint4*)(Xs + tq * ROW + kb * 2) = v;
        v.x = (unsigned)cl_[0] | ((unsigned)cl_[1] << 16);
        v.y = (unsigned)cl_[2] | ((unsigned)cl_[3] << 16);
        v.z = (unsigned)cl_[4] | ((unsigned)cl_[5] << 16);
        v.w = (unsigned)cl_[6] | ((unsigned)cl_[7] << 16);
        *(uint4*)(Xs + PLANE + tq * ROW + kb * 2) = v;
        v.x = (unsigned)sh_[0] | ((unsigned)sh_[1] << 16);
        v.y = (unsigned)sh_[2] | ((unsigned)sh_[3] << 16);
        v.z = (unsigned)sh_[4] | ((unsigned)sh_[5] << 16);
        v.w = (unsigned)sh_[6] | ((unsigned)sh_[7] << 16);
        *(uint4*)(Xs + tq * ROW + (128 + kb) * 2) = v;
        v.x = (unsigned)sl_[0] | ((unsigned)sl_[1] << 16);
        v.y = (unsigned)sl_[2] | ((unsigned)sl_[3] << 16);
        v.z = (unsigned)sl_[4] | ((unsigned)sl_[5] << 16);
        v.w = (unsigned)sl_[6] | ((unsigned)sl_[7] << 16);
        *(uint4*)(Xs + PLANE + tq * ROW + (128 + kb) * 2) = v;
      }
    }
  }
  __syncthreads();

  const int w = t >> 6, lane = t & 63;
  const int quad = lane >> 4, ml = lane & 15;
  const unsigned int bvoff = (unsigned int)lane * 16u;

#pragma unroll
  for (int layer = 0; layer < 2; ++layer) {
    const unsigned short* wb = wmlp + layer * 131072;
    f4v acc[4][4];
#pragma unroll
    for (int i = 0; i < 4; ++i)
#pragma unroll
      for (int j = 0; j < 4; ++j) acc[i][j] = (f4v){0.0f, 0.0f, 0.0f, 0.0f};
#pragma unroll
    for (int kstep = 0; kstep < 8; ++kstep) {
      s8v Bh[4], Bl[4];
#pragma unroll
      for (int j = 0; j < 4; ++j) {
        unsigned int off = (unsigned int)((w * 4 + j) * 8 + kstep) * 1024u + bvoff;
        Bh[j] = *(const s8v*)((const char*)wb + off);
        Bl[j] = *(const s8v*)((const char*)(wb + 65536) + off);
      }
#pragma unroll
      for (int i = 0; i < 4; ++i) {
        const int aoff = (i * 16 + ml) * ROW + (kstep * 32 + quad * 8) * 2;
        s8v Ah = *(const s8v*)(Xs + aoff);
        s8v Al = *(const s8v*)(Xs + PLANE + aoff);
#pragma unroll
        for (int j = 0; j < 4; ++j) {
          acc[i][j] = __builtin_amdgcn_mfma_f32_16x16x32_bf16(Ah, Bh[j], acc[i][j], 0, 0, 0);
          acc[i][j] = __builtin_amdgcn_mfma_f32_16x16x32_bf16(Al, Bh[j], acc[i][j], 0, 0, 0);
          acc[i][j] = __builtin_amdgcn_mfma_f32_16x16x32_bf16(Ah, Bl[j], acc[i][j], 0, 0, 0);
        }
      }
    }
    __syncthreads();
    const float* bs = layer ? b2 : b1;
    float bj[4];
#pragma unroll
    for (int j = 0; j < 4; ++j) bj[j] = bs[w * 64 + j * 16 + ml];
    if (layer == 0) {
#pragma unroll
      for (int i = 0; i < 4; ++i)
#pragma unroll
        for (int j = 0; j < 4; ++j)
#pragma unroll
          for (int reg = 0; reg < 4; ++reg) {
            int m = i * 16 + quad * 4 + reg;
            int n = w * 64 + j * 16 + ml;
            float v = fmaxf(acc[i][j][reg] + bj[j], 0.0f);
            unsigned short hi = f2bf(v);
            unsigned short lo = f2bf(v - bf2f(hi));
            *(unsigned short*)(Xs + m * ROW + n * 2) = hi;
            *(unsigned short*)(Xs + PLANE + m * ROW + n * 2) = lo;
          }
    } else {
#pragma unroll
      for (int i = 0; i < 4; ++i)
#pragma unroll
        for (int j = 0; j < 4; ++j)
#pragma unroll
          for (int reg = 0; reg < 4; ++reg) {
            int m = i * 16 + quad * 4 + reg;
            int n = w * 64 + j * 16 + ml;
            float v = fmaxf(acc[i][j][reg] + bj[j], 0.0f);
            *(float*)(Xs + ((size_t)m * 264 + n) * 4) = v;
          }
    }
    __syncthreads();
  }

  {
    const int tq = t >> 2, ts = t & 3;
    const float* xr = (const float*)(Xs + (size_t)tq * 264 * 4);
    float c0 = 0, c1 = 0, c2 = 0;
    for (int k = ts * 64; k < ts * 64 + 64; ++k) {
      float xv = xr[k];
      c0 += xv * w3[k];
      c1 += xv * w3[256 + k];
      c2 += xv * w3[512 + k];
    }
    c0 += __shfl_down(c0, 2, 4); c0 += __shfl_down(c0, 1, 4);
    c1 += __shfl_down(c1, 2, 4); c1 += __shfl_down(c1, 1, 4);
    c2 += __shfl_down(c2, 2, 4); c2 += __shfl_down(c2, 1, 4);
    if (ts == 0) {
      const int qg = q0 + tq;
      float* o = out + (size_t)qg * 3;
      o[0] = c0 + b3[0];
      o[1] = c1 + b3[1];
      o[2] = c2 + b3[2];
    }
  }
}

// ---------------- launch ----------------
extern "C" void kernel_launch(void* const* d_in, const int* in_sizes, int n_in,
                              void* d_out, int out_size, void* d_ws, size_t ws_size,
                              hipStream_t stream) {
  (void)in_sizes; (void)n_in; (void)out_size; (void)ws_size;
  const float* feat   = (const float*)d_in[0];
  const float* coord  = (const float*)d_in[1];
  const float* cell   = (const float*)d_in[2];
  const float* cls_w1 = (const float*)d_in[3];
  const float* cls_b1 = (const float*)d_in[4];
  const float* cls_w2 = (const float*)d_in[5];
  const float* cls_b2 = (const float*)d_in[6];
  const float* sigx   = (const float*)d_in[7];
  const float* sigy   = (const float*)d_in[8];
  const float* opac   = (const float*)d_in[9];
  const float* rho    = (const float*)d_in[10];
  const float* coef_w = (const float*)d_in[11];
  const float* coef_b = (const float*)d_in[12];
  const float* freq_w = (const float*)d_in[13];
  const float* freq_b = (const float*)d_in[14];
  const float* phw    = (const float*)d_in[15];
  const float* w1     = (const float*)d_in[16];
  const float* b1     = (const float*)d_in[17];
  const float* w2     = (const float*)d_in[18];
  const float* b2     = (const float*)d_in[19];
  const float* w3     = (const float*)d_in[20];
  const float* b3     = (const float*)d_in[21];

  char* ws = (char*)d_ws;
  unsigned short* fbh = (unsigned short*)(ws + OFF_FBH);
  unsigned short* fbl = (unsigned short*)(ws + OFF_FBL);
  unsigned short* gfh = (unsigned short*)(ws + OFF_GFH);   // overlap fb (dead after conv1)
  unsigned short* gfl = (unsigned short*)(ws + OFF_GFL);
  float* h_buf = (float*)(ws + OFF_H);
  unsigned short* cfb = (unsigned short*)(ws + OFF_CF);    // fp16
  unsigned short* wph = (unsigned short*)(ws + OFF_WPH);
  unsigned short* wpl = (unsigned short*)(ws + OFF_WPL);
  unsigned short* w1h = (unsigned short*)(ws + OFF_W1H);
  unsigned short* w1l = (unsigned short*)(ws + OFF_W1L);
  unsigned short* wmlp = (unsigned short*)(ws + OFF_WMLP);
  float* wsums = (float*)(ws + OFF_WSUM);
  float* wk    = (float*)(ws + OFF_WK);
  float* outp  = (float*)d_out;

  hipLaunchKernelGGL(k_init, dim3(1), dim3(256), 0, stream, wsums);
  hipLaunchKernelGGL(k_prepw, dim3(1152), dim3(256), 0, stream, coef_w, freq_w, wph, wpl);
  hipLaunchKernelGGL(k_prepw1, dim3(144), dim3(256), 0, stream, cls_w1, w1h, w1l);
  hipLaunchKernelGGL(k_prepmlp, dim3(512), dim3(256), 0, stream, w1, w2, wmlp);
  hipLaunchKernelGGL(k_prepfeat, dim3(784), dim3(256), 0, stream, feat, fbh, fbl);
  hipLaunchKernelGGL(k_conv1_mfma, dim3(392), dim3(256), 0, stream,
                     fbh, fbl, w1h, w1l, cls_b1, h_buf);
  hipLaunchKernelGGL(k_wavg, dim3(196), dim3(256), 0, stream,
                     h_buf, cls_w2, cls_b2, sigx, sigy, opac, rho, wsums);
  hipLaunchKernelGGL(k_finalize, dim3(1), dim3(256), 0, stream, wsums, wk);

  for (int b = 0; b < kB; ++b) {
    const float* feat_b = feat + (size_t)b * 64 * kH1 * kH1;
    hipLaunchKernelGGL(k_splat, dim3(256), dim3(256), 0, stream, feat_b, wk, gfh, gfl);
    hipLaunchKernelGGL(k_conv2_mfma, dim3(1568), dim3(256), 0, stream,
                       gfh, gfl, wph, wpl, coef_b, freq_b, cfb);
    hipLaunchKernelGGL(k_query_mfma, dim3(784), dim3(256), 0, stream,
                       cfb, coord, cell, phw, wmlp, b1, b2, w3, b3, outp, b * kQ);
  }
}

// Round 12
// 1060.320 us; speedup vs baseline: 1.0393x; 1.0393x over previous
//
#include <hip/hip_runtime.h>
#include <hip/hip_fp16.h>
#include <math.h>

// ---------------- problem constants ----------------
namespace {
constexpr int kB   = 4;
constexpr int kNG  = 100;
constexpr int kH1  = 112;            // feat H/W
constexpr int kH2  = 224;            // upscaled H/W
constexpr int kQ   = kH2 * kH2;      // 50176 queries per batch image
constexpr int kP1  = kH1 * kH1;      // 12544 pixels per image (feat res)

// workspace layout (bytes).
constexpr size_t OFF_FBH  = 0;                       // bf16 feat hi [4*12544][64] = 6,422,528
constexpr size_t OFF_FBL  = 6422528;                 // bf16 feat lo
constexpr size_t OFF_GFH  = 0;                       // bf16 gfeat hi [224*224][64] (overlaps fb)
constexpr size_t OFF_GFL  = 6422528;                 // bf16 gfeat lo
constexpr size_t OFF_H    = 12845056;                // fp32 h [4*12544][64] = 12,845,056
constexpr size_t OFF_CF   = 25690112;                // fp16 cf [224*224][512] = 51,380,224
constexpr size_t OFF_WPH  = OFF_CF + 51380224;       // conv2 W frag-order hi, 589,824
constexpr size_t OFF_WPL  = OFF_WPH + 589824;        // conv2 W frag-order lo
constexpr size_t OFF_W1H  = OFF_WPL + 589824;        // conv1 W frag-order hi, 73,728
constexpr size_t OFF_W1L  = OFF_W1H + 73728;
constexpr size_t OFF_WMLP = OFF_W1L + 73728;         // mlp W1/W2 frag-order hi/lo, 524,288
constexpr size_t OFF_WSUM = OFF_WMLP + 524288;
constexpr size_t OFF_WK   = OFF_WSUM + 1024;
// total ~79 MB
}  // namespace

using s8v = __attribute__((ext_vector_type(8))) short;   // 8 bf16 (4 VGPRs)
using f4v = __attribute__((ext_vector_type(4))) float;   // MFMA acc
using u4v = __attribute__((ext_vector_type(4))) unsigned int;  // native vec for nt-store

__device__ __forceinline__ unsigned short f2bf(float f) {
  unsigned int u = __float_as_uint(f);
  unsigned int r = u + 0x7fffu + ((u >> 16) & 1u);   // round-nearest-even
  return (unsigned short)(r >> 16);
}
__device__ __forceinline__ float bf2f(unsigned short h) {
  return __uint_as_float((unsigned int)h << 16);
}
__device__ __forceinline__ unsigned short f2h(float f) {
  return __builtin_bit_cast(unsigned short, __float2half(f));  // RNE
}
__device__ __forceinline__ float h2f(unsigned short u) {
  return __half2float(__builtin_bit_cast(__half, u));
}

// ---------------- tiny helpers ----------------
__global__ void k_init(float* wsums) {
  int t = threadIdx.x;
  if (t < 196) wsums[t] = 0.0f;
}

// feat fp32 channel-major -> pixel-major bf16 hi/lo (LDS transpose, coalesced both sides)
__global__ __launch_bounds__(256) void k_prepfeat(const float* __restrict__ feat,
                                                  unsigned short* __restrict__ fbh,
                                                  unsigned short* __restrict__ fbl) {
  __shared__ float ls[64 * 65];
  const int t = threadIdx.x;
  const int b = blockIdx.x / 196;       // image
  const int seg = blockIdx.x % 196;     // 64-pixel segment within image
  const int pixbase = seg * 64;
  for (int idx = t; idx < 4096; idx += 256) {
    int ci = idx >> 6, px = idx & 63;
    ls[px * 65 + ci] = feat[((size_t)(b * 64 + ci)) * kP1 + pixbase + px];
  }
  __syncthreads();
  for (int idx = t; idx < 4096; idx += 256) {
    int px = idx >> 6, ci = idx & 63;
    float v = ls[px * 65 + ci];
    unsigned short hi = f2bf(v);
    unsigned short lo = f2bf(v - bf2f(hi));
    size_t o = ((size_t)(b * kP1 + pixbase + px)) * 64 + ci;
    fbh[o] = hi;
    fbl[o] = lo;
  }
}

// Pack conv2 weights into MFMA B-fragment order, split bf16 hi/lo.
__global__ void k_prepw(const float* __restrict__ cw, const float* __restrict__ fw,
                        unsigned short* __restrict__ wph, unsigned short* __restrict__ wpl) {
  int e = blockIdx.x * 256 + threadIdx.x;   // 512*576 = 294912
  int co = e / 576, k = e % 576;
  int ci = k & 63, kk = k >> 6;
  float v = (co < 256) ? cw[co * 576 + ci * 9 + kk] : fw[(co - 256) * 576 + ci * 9 + kk];
  unsigned short hi = f2bf(v);
  unsigned short lo = f2bf(v - bf2f(hi));
  int n16 = co >> 4, nl = co & 15;
  int kstep = k >> 5, kr = k & 31;
  int dst = ((n16 * 18 + kstep) * 64 + (kr >> 3) * 16 + nl) * 8 + (kr & 7);
  wph[dst] = hi;
  wpl[dst] = lo;
}

// Pack conv1 weights (64 co) into the same B-frag order.
__global__ void k_prepw1(const float* __restrict__ w1src,
                         unsigned short* __restrict__ wph, unsigned short* __restrict__ wpl) {
  int e = blockIdx.x * 256 + threadIdx.x;   // 64*576 = 36864
  int co = e / 576, k = e % 576;
  int ci = k & 63, kk = k >> 6;
  float v = w1src[co * 576 + ci * 9 + kk];
  unsigned short hi = f2bf(v);
  unsigned short lo = f2bf(v - bf2f(hi));
  int n16 = co >> 4, nl = co & 15;
  int kstep = k >> 5, kr = k & 31;
  int dst = ((n16 * 18 + kstep) * 64 + (kr >> 3) * 16 + nl) * 8 + (kr & 7);
  wph[dst] = hi;
  wpl[dst] = lo;
}

// Pack MLP W1/W2 into B-frag order hi/lo. wmlp layout: [mat][hi/lo][65536 bf16]
__global__ void k_prepmlp(const float* __restrict__ w1, const float* __restrict__ w2,
                          unsigned short* __restrict__ wp) {
  int e = blockIdx.x * 256 + threadIdx.x;   // 131072
  int mat = e >> 16, idx = e & 65535;
  int j = idx >> 8, k = idx & 255;
  float v = (mat ? w2 : w1)[j * 256 + k];
  unsigned short hi = f2bf(v);
  unsigned short lo = f2bf(v - bf2f(hi));
  int n16 = j >> 4, nl = j & 15;
  int kstep = k >> 5, kr = k & 31;
  int dst = ((n16 * 8 + kstep) * 64 + (kr >> 3) * 16 + nl) * 8 + (kr & 7);
  wp[mat * 131072 + dst] = hi;
  wp[mat * 131072 + 65536 + dst] = lo;
}

// ---------------- conv1 as bf16x3 MFMA implicit GEMM, ReLU, pixel-major fp32 out ----------------
__global__ __launch_bounds__(256) void k_conv1_mfma(
    const unsigned short* __restrict__ fbh, const unsigned short* __restrict__ fbl,
    const unsigned short* __restrict__ wph, const unsigned short* __restrict__ wpl,
    const float* __restrict__ bias, float* __restrict__ outp) {  // h [4*12544][64]
  __shared__ __attribute__((aligned(16))) char Asb[2 * 180 * 144];  // 51,840 B
  const int t = threadIdx.x;
  const int blk = blockIdx.x;          // 4 b * 7 ty * 14 tx = 392
  const int b = blk / 98;
  const int mt = blk % 98;
  const int ty = mt / 14, tx = mt % 14;
  const int py0 = ty * 16, px0 = tx * 8;

  for (int idx = t; idx < 2880; idx += 256) {
    int plane = idx >= 1440;
    int r2 = plane ? idx - 1440 : idx;
    int p = r2 >> 3, c8 = r2 & 7;
    int pr = p / 10, pc = p % 10;
    int gy = py0 - 1 + pr, gx = px0 - 1 + pc;
    uint4 u = make_uint4(0u, 0u, 0u, 0u);
    if (gy >= 0 && gy < kH1 && gx >= 0 && gx < kH1) {
      const unsigned short* src = (plane ? fbl : fbh) +
          ((size_t)(b * kP1 + gy * kH1 + gx)) * 64 + c8 * 8;
      u = *(const uint4*)src;
    }
    *(uint4*)(Asb + plane * 25920 + p * 144 + c8 * 16) = u;
  }
  __syncthreads();

  const int w = t >> 6, lane = t & 63;
  const int quad = lane >> 4, ml = lane & 15;

  f4v acc[8];
#pragma unroll
  for (int i = 0; i < 8; ++i) acc[i] = (f4v){0.0f, 0.0f, 0.0f, 0.0f};

  const unsigned int bvoff = (unsigned int)lane * 16u;
#pragma unroll
  for (int kk = 0; kk < 9; ++kk) {
    const int ky = kk / 3, kx = kk % 3;
#pragma unroll
    for (int cs = 0; cs < 2; ++cs) {
      const int kstep = kk * 2 + cs;
      unsigned int off = ((unsigned int)(w * 18 + kstep)) * 1024u + bvoff;
      s8v Bh = *(const s8v*)((const char*)wph + off);
      s8v Bl = *(const s8v*)((const char*)wpl + off);
#pragma unroll
      for (int i = 0; i < 8; ++i) {
        const int aoff = ((2 * i + (ml >> 3) + ky) * 10 + (ml & 7) + kx) * 144 + cs * 64 + quad * 16;
        s8v Ah = *(const s8v*)(Asb + aoff);
        s8v Al = *(const s8v*)(Asb + 25920 + aoff);
        acc[i] = __builtin_amdgcn_mfma_f32_16x16x32_bf16(Ah, Bh, acc[i], 0, 0, 0);
        acc[i] = __builtin_amdgcn_mfma_f32_16x16x32_bf16(Al, Bh, acc[i], 0, 0, 0);
        acc[i] = __builtin_amdgcn_mfma_f32_16x16x32_bf16(Ah, Bl, acc[i], 0, 0, 0);
      }
    }
  }

  const float bv = bias[w * 16 + ml];
#pragma unroll
  for (int i = 0; i < 8; ++i)
#pragma unroll
    for (int reg = 0; reg < 4; ++reg) {
      int m = i * 16 + quad * 4 + reg;
      int Y = py0 + (m >> 3), X = px0 + (m & 7);
      outp[((size_t)(b * kP1 + Y * kH1 + X)) * 64 + w * 16 + ml] =
          fmaxf(acc[i][reg] + bv, 0.0f);
    }
}

// ---------------- 1x1 conv + softmax + weighted sums -> wsums[4][49] ----------------
__global__ __launch_bounds__(256) void k_wavg(
    const float* __restrict__ h, const float* __restrict__ w2, const float* __restrict__ b2,
    const float* __restrict__ sx, const float* __restrict__ sy,
    const float* __restrict__ op, const float* __restrict__ rho,
    float* __restrict__ wsums) {
  __shared__ float w2s[kNG * 64];
  __shared__ float prm[4 * kNG];
  __shared__ float b2s[kNG];
  __shared__ float pl[196];
  const int t = threadIdx.x;
  for (int i = t; i < kNG * 64; i += 256) w2s[i] = w2[i];
  if (t < kNG) {
    prm[t] = sx[t];
    prm[kNG + t] = sy[t];
    prm[2 * kNG + t] = op[t];
    prm[3 * kNG + t] = rho[t];
    b2s[t] = b2[t];
  }
  if (t < 196) pl[t] = 0.0f;
  __syncthreads();
  const int id = blockIdx.x * 256 + t;
  float hreg[64];
  const float4* hp = (const float4*)(h + (size_t)id * 64);
#pragma unroll
  for (int i = 0; i < 16; ++i) {
    float4 v = hp[i];
    hreg[4 * i] = v.x; hreg[4 * i + 1] = v.y;
    hreg[4 * i + 2] = v.z; hreg[4 * i + 3] = v.w;
  }
  float S = 0, Sx = 0, Sy = 0, So = 0, Sr = 0;
  for (int g = 0; g < kNG; ++g) {
    float d = b2s[g];
    const float4* wp = (const float4*)(w2s + g * 64);
#pragma unroll
    for (int i = 0; i < 16; ++i) {
      float4 w = wp[i];
      d += hreg[4 * i] * w.x + hreg[4 * i + 1] * w.y +
           hreg[4 * i + 2] * w.z + hreg[4 * i + 3] * w.w;
    }
    float e = expf(d);
    S += e;
    Sx += e * prm[g];
    Sy += e * prm[kNG + g];
    So += e * prm[2 * kNG + g];
    Sr += e * prm[3 * kNG + g];
  }
  const int rem = id % (kH1 * kH1);
  const int p = ((rem / kH1) % 7) * 7 + ((rem % kH1) % 7);
  const float inv = 1.0f / S;
  atomicAdd(&pl[p], Sx * inv);
  atomicAdd(&pl[49 + p], Sy * inv);
  atomicAdd(&pl[98 + p], So * inv);
  atomicAdd(&pl[147 + p], Sr * inv);
  __syncthreads();
  if (t < 196) atomicAdd(&wsums[t], pl[t]);
}

// ---------------- build wk[p][h][w] ----------------
__global__ __launch_bounds__(256) void k_finalize(const float* __restrict__ wsums,
                                                  float* __restrict__ wk) {
  __shared__ float kern_s[49 * 25];
  __shared__ float wavg_s[196];
  const int t = threadIdx.x;
  if (t < 196) wavg_s[t] = wsums[t] * (1.0f / 1024.0f);
  __syncthreads();
  if (t < 49) {
    float wsx = wavg_s[t], wsy = wavg_s[49 + t], wr = wavg_s[147 + t];
    float c00 = wsx * wsx + 1e-5f;
    float c11 = wsy * wsy + 1e-5f;
    float c01 = wr * wsx * wsy;
    float det = c00 * c11 - c01 * c01;
    float i00 = c11 / det, i11 = c00 / det, i01 = -c01 / det;
    float nrm = 1.0f / (2.0f * 3.14159265358979323846f * sqrtf(det));
    float vals[25];
    float mx = -1e30f;
#pragma unroll
    for (int i = 0; i < 5; ++i) {
#pragma unroll
      for (int j = 0; j < 5; ++j) {
        float yv = -5.0f + 2.5f * (float)i;
        float xv = -5.0f + 2.5f * (float)j;
        float z = -0.5f * (i00 * xv * xv + 2.0f * i01 * xv * yv + i11 * yv * yv);
        float v = expf(z) * nrm;
        vals[i * 5 + j] = v;
        mx = fmaxf(mx, v);
      }
    }
#pragma unroll
    for (int k = 0; k < 25; ++k) kern_s[t * 25 + k] = vals[k] / mx;
  }
  __syncthreads();
  for (int idx = t; idx < 49 * 196; idx += 256) {
    const int p = idx / 196;
    const int hw = idx % 196;
    const int hh = hw / 14, ww = hw % 14;
    float txv = (0.5f - (float)(p / 7) / 7.0f) * 2.0f;
    float tyv = (0.5f - (float)(p % 7) / 7.0f) * 2.0f;
    float gxv = (-1.0f + (float)ww * (2.0f / 13.0f)) + txv;
    float gyv = (-1.0f + (float)hh * (2.0f / 13.0f)) + tyv;
    float pxv = (gxv + 1.0f) * 0.5f * 13.0f;
    float pyv = (gyv + 1.0f) * 0.5f * 13.0f;
    float x0f = floorf(pxv), y0f = floorf(pyv);
    int x0 = (int)x0f, y0 = (int)y0f;
    float wx = pxv - x0f, wy = pyv - y0f;
    auto samp = [&](int yi, int xi) -> float {
      if (yi < 4 || yi >= 9 || xi < 4 || xi >= 9) return 0.0f;
      return kern_s[p * 25 + (yi - 4) * 5 + (xi - 4)];
    };
    float kt = samp(y0, x0) * (1.0f - wy) * (1.0f - wx) +
               samp(y0, x0 + 1) * (1.0f - wy) * wx +
               samp(y0 + 1, x0) * wy * (1.0f - wx) +
               samp(y0 + 1, x0 + 1) * wy * wx;
    wk[idx] = wavg_s[98 + p] * kt;
  }
}

// ---------------- splat (ONE image) -> pixel-major bf16 hi/lo gfeat ----------------
__global__ __launch_bounds__(256) void k_splat(const float* __restrict__ feat,
                                               const float* __restrict__ wk,
                                               unsigned short* __restrict__ gfh,
                                               unsigned short* __restrict__ gfl) {
  __shared__ float fs[64 * 49];
  __shared__ float wks[49 * 196];
  const int t = threadIdx.x;
  const int rem = blockIdx.x;   // 256 tiles
  const int ry = rem >> 4, rx = rem & 15;
  for (int idx = t; idx < 64 * 49; idx += 256) {
    int ci = idx / 49, p = idx % 49;
    int gy = ry * 7 + p / 7, gx = rx * 7 + p % 7;
    fs[idx] = feat[((size_t)ci * kH1 + gy) * kH1 + gx];
  }
  for (int idx = t; idx < 49 * 196; idx += 256) wks[idx] = wk[idx];
  __syncthreads();
  const int ci = t & 63;
  const int s = t >> 6;
  const int h0 = (s >> 1) * 7, w0 = (s & 1) * 7;
  float acc[49];
#pragma unroll
  for (int i = 0; i < 49; ++i) acc[i] = 0.0f;
  for (int p = 0; p < 49; ++p) {
    float f = fs[ci * 49 + p];
#pragma unroll
    for (int i = 0; i < 7; ++i)
#pragma unroll
      for (int j = 0; j < 7; ++j)
        acc[i * 7 + j] += f * wks[p * 196 + (h0 + i) * 14 + (w0 + j)];
  }
#pragma unroll
  for (int i = 0; i < 7; ++i)
#pragma unroll
    for (int j = 0; j < 7; ++j) {
      int Y = ry * 14 + h0 + i;
      int X = rx * 14 + w0 + j;
      float v = fminf(fmaxf(acc[i * 7 + j], 0.0f), 1.0f);
      unsigned short hi = f2bf(v);
      unsigned short lo = f2bf(v - bf2f(hi));
      size_t o = ((size_t)Y * kH2 + X) * 64 + ci;
      gfh[o] = hi;
      gfl[o] = lo;
    }
}

// ---------------- conv2 as bf16x3 MFMA implicit GEMM (ONE image), fp16 output ----------------
// Round-10 configuration restored (M=128 tile, free VGPR alloc = 256, no spill,
// hbm 170 MB, 133 us). Round-11's M=64 split doubled HBM traffic and regressed.
__global__ __launch_bounds__(256) void k_conv2_mfma(
    const unsigned short* __restrict__ gfh, const unsigned short* __restrict__ gfl,
    const unsigned short* __restrict__ wph, const unsigned short* __restrict__ wpl,
    const float* __restrict__ coef_b, const float* __restrict__ freq_b,
    unsigned short* __restrict__ outp) {     // fp16 [224*224][512]
  __shared__ __attribute__((aligned(16))) char Asb[2 * 180 * 144];  // 51,840 B
  const int t = threadIdx.x;
  const int blk = blockIdx.x;       // 392 Mtiles * 2 Nhalves
  const int nb = blk & 1;
  const int mt = blk >> 1;
  const int ty = mt / 28, tx = mt % 28;
  const int py0 = ty * 16, px0 = tx * 8;

  for (int idx = t; idx < 2880; idx += 256) {
    int plane = idx >= 1440;
    int r2 = plane ? idx - 1440 : idx;
    int p = r2 >> 3, c8 = r2 & 7;
    int pr = p / 10, pc = p % 10;
    int gy = py0 - 1 + pr, gx = px0 - 1 + pc;
    uint4 u = make_uint4(0u, 0u, 0u, 0u);
    if (gy >= 0 && gy < kH2 && gx >= 0 && gx < kH2) {
      const unsigned short* src = (plane ? gfl : gfh) + ((size_t)(gy * kH2 + gx)) * 64 + c8 * 8;
      u = *(const uint4*)src;
    }
    *(uint4*)(Asb + plane * 25920 + p * 144 + c8 * 16) = u;
  }
  __syncthreads();

  const int w = t >> 6, lane = t & 63;
  const int quad = lane >> 4, ml = lane & 15;
  const int abase = (((ml >> 3) * 10) + (ml & 7)) * 144 + quad * 16;
  const int n16base = nb * 16 + w * 4;
  const unsigned int bvoff = (unsigned int)lane * 16u;

  f4v acc[8][4];
#pragma unroll
  for (int i = 0; i < 8; ++i)
#pragma unroll
    for (int j = 0; j < 4; ++j) acc[i][j] = (f4v){0.0f, 0.0f, 0.0f, 0.0f};

#pragma unroll
  for (int kk = 0; kk < 9; ++kk) {
    const int ky = kk / 3, kx = kk % 3;
#pragma unroll
    for (int cs = 0; cs < 2; ++cs) {
      const int kstep = kk * 2 + cs;
      s8v Bh[4], Bl[4];
#pragma unroll
      for (int j = 0; j < 4; ++j) {
        unsigned int off = ((unsigned int)(n16base + j) * 18u + (unsigned int)kstep) * 1024u + bvoff;
        Bh[j] = *(const s8v*)((const char*)wph + off);
        Bl[j] = *(const s8v*)((const char*)wpl + off);
      }
#pragma unroll
      for (int i = 0; i < 8; ++i) {
        const int aoff = ((2 * i + ky) * 10 + kx) * 144 + cs * 64 + abase;
        s8v Ah = *(const s8v*)(Asb + aoff);
        s8v Al = *(const s8v*)(Asb + 25920 + aoff);
#pragma unroll
        for (int j = 0; j < 4; ++j) {
          acc[i][j] = __builtin_amdgcn_mfma_f32_16x16x32_bf16(Ah, Bh[j], acc[i][j], 0, 0, 0);
          acc[i][j] = __builtin_amdgcn_mfma_f32_16x16x32_bf16(Al, Bh[j], acc[i][j], 0, 0, 0);
          acc[i][j] = __builtin_amdgcn_mfma_f32_16x16x32_bf16(Ah, Bl[j], acc[i][j], 0, 0, 0);
        }
      }
    }
  }

  // ---- epilogue via LDS, convert to fp16, nontemporal full-line stores ----
  const int cobase = nb * 256 + w * 64;
  float bj[4];
#pragma unroll
  for (int j = 0; j < 4; ++j) {
    int co = cobase + j * 16 + ml;
    bj[j] = (co < 256) ? coef_b[co] : freq_b[co - 256];
  }
  __syncthreads();               // Asb (A-tile) dead; reuse as staging
  float* Ls = (float*)Asb;       // [32 pixels][268 floats]
  const int pq = t >> 3;
  const int ts = t & 7;
#pragma unroll
  for (int c = 0; c < 4; ++c) {
#pragma unroll
    for (int ii = 0; ii < 2; ++ii) {
      const int i = c * 2 + ii;
#pragma unroll
      for (int j = 0; j < 4; ++j)
#pragma unroll
        for (int reg = 0; reg < 4; ++reg) {
          const int p = ii * 16 + quad * 4 + reg;           // 0..31
          Ls[p * 268 + w * 64 + j * 16 + ml] = acc[i][j][reg] + bj[j];
        }
    }
    __syncthreads();
    const int m = c * 32 + pq;                              // pixel in M-tile
    const int Y = py0 + (m >> 3), X = px0 + (m & 7);
    unsigned short* orow = outp + ((size_t)(Y * kH2 + X)) * 512 + nb * 256;
    const float* lrow = Ls + pq * 268;
#pragma unroll
    for (int u = 0; u < 4; ++u) {
      float4 a = *(const float4*)(lrow + u * 64 + ts * 8);
      float4 b = *(const float4*)(lrow + u * 64 + ts * 8 + 4);
      u4v v;
      v.x = (unsigned)f2h(a.x) | ((unsigned)f2h(a.y) << 16);
      v.y = (unsigned)f2h(a.z) | ((unsigned)f2h(a.w) << 16);
      v.z = (unsigned)f2h(b.x) | ((unsigned)f2h(b.y) << 16);
      v.w = (unsigned)f2h(b.z) | ((unsigned)f2h(b.w) << 16);
      __builtin_nontemporal_store(v, (u4v*)(orow + u * 64 + ts * 8));
    }
    __syncthreads();
  }
}

// ---------------- fused query (ONE image): fp16 gather + basis + bf16x3 MFMA MLP ----------------
// Round 12: 32-query blocks (Xs 33.8 KB -> up to 4 blocks/CU = 16 waves/CU,
// vs 2 blocks at 64 queries). Wave tile M=32 (acc[2][4]); W stays L2-resident
// so the extra request traffic costs L2 BW, not HBM (unlike conv2's r11 case).
// No min-waves clause (r9 lesson).
__global__ __launch_bounds__(256) void k_query_mfma(
    const unsigned short* __restrict__ cfh,    // fp16 cf
    const float* __restrict__ coord,
    const float* __restrict__ cell, const float* __restrict__ phw,
    const unsigned short* __restrict__ wmlp,   // [2][hi/lo][65536]
    const float* __restrict__ b1, const float* __restrict__ b2,
    const float* __restrict__ w3, const float* __restrict__ b3,
    float* __restrict__ out, int q_base) {
  __shared__ __attribute__((aligned(16))) char Xs[2 * 32 * 264 * 2];  // 33,792 B
  constexpr int ROW = 264 * 2;
  constexpr int PLANE = 32 * 264 * 2;
  const int t = threadIdx.x;
  const int q0 = q_base + blockIdx.x * 32;

  // ---- phase 1: gather + basis (8 threads per query, 32 queries) ----
  {
    const int tq = t >> 3, ts = t & 7;
    const int qg = q0 + tq;
    float gy = coord[(size_t)qg * 2 + 0];
    float gx = coord[(size_t)qg * 2 + 1];
    float fx = ((gx + 1.0f) * 224.0f - 1.0f) * 0.5f;
    float fy = ((gy + 1.0f) * 224.0f - 1.0f) * 0.5f;
    int ix = (int)rintf(fx);
    int iy = (int)rintf(fy);
    bool ok = (ix >= 0) && (ix < 224) && (iy >= 0) && (iy < 224);
    int ixc = min(max(ix, 0), 223);
    int iyc = min(max(iy, 0), 223);
    float m = ok ? 1.0f : 0.0f;
    float qcy = ok ? (-1.0f + (1.0f / 224.0f) + (2.0f / 224.0f) * (float)iyc) : 0.0f;
    float qcx = ok ? (-1.0f + (1.0f / 224.0f) + (2.0f / 224.0f) * (float)ixc) : 0.0f;
    float rel0 = (gy - qcy) * 224.0f;
    float rel1 = (gx - qcx) * 224.0f;
    float rc0 = cell[(size_t)qg * 2 + 0] * 224.0f;
    float rc1 = cell[(size_t)qg * 2 + 1] * 224.0f;
    const unsigned short* base = cfh + (((size_t)iyc * kH2 + ixc) * 512);
    unsigned short ch_[8], cl_[8], sh_[8], sl_[8];
#pragma unroll
    for (int u = 0; u < 4; ++u) {
      const int k4 = ts * 16 + u * 4;
      ushort4 clo = *(const ushort4*)(base + k4);
      ushort4 chi = *(const ushort4*)(base + 128 + k4);
      ushort4 f0 = *(const ushort4*)(base + 256 + 2 * k4);
      ushort4 f1 = *(const ushort4*)(base + 256 + 2 * k4 + 4);
      float fr[8] = {h2f(f0.x), h2f(f0.y), h2f(f0.z), h2f(f0.w),
                     h2f(f1.x), h2f(f1.y), h2f(f1.z), h2f(f1.w)};
      float cl4[4] = {h2f(clo.x), h2f(clo.y), h2f(clo.z), h2f(clo.w)};
      float ch4[4] = {h2f(chi.x), h2f(chi.y), h2f(chi.z), h2f(chi.w)};
#pragma unroll
      for (int e = 0; e < 4; ++e) {
        const int k = k4 + e;
        float ph = rc0 * phw[2 * k] + rc1 * phw[2 * k + 1];
        float s = m * (fr[2 * e] * rel0 + fr[2 * e + 1] * rel1) + ph;
        float sv, cv;
        sincospif(s, &sv, &cv);
        float xc = m * cl4[e] * cv;
        float xsn = m * ch4[e] * sv;
        const int sl = (u & 1) * 4 + e;
        unsigned short h1_ = f2bf(xc);
        ch_[sl] = h1_; cl_[sl] = f2bf(xc - bf2f(h1_));
        unsigned short h2_ = f2bf(xsn);
        sh_[sl] = h2_; sl_[sl] = f2bf(xsn - bf2f(h2_));
      }
      if (u & 1) {
        const int kb = ts * 16 + (u - 1) * 4;
        uint4 v;
        v.x = (unsigned)ch_[0] | ((unsigned)ch_[1] << 16);
        v.y = (unsigned)ch_[2] | ((unsigned)ch_[3] << 16);
        v.z = (unsigned)ch_[4] | ((unsigned)ch_[5] << 16);
        v.w = (unsigned)ch_[6] | ((unsigned)ch_[7] << 16);
        *(uint4*)(Xs + tq * ROW + kb * 2) = v;
        v.x = (unsigned)cl_[0] | ((unsigned)cl_[1] << 16);
        v.y = (unsigned)cl_[2] | ((unsigned)cl_[3] << 16);
        v.z = (unsigned)cl_[4] | ((unsigned)cl_[5] << 16);
        v.w = (unsigned)cl_[6] | ((unsigned)cl_[7] << 16);
        *(uint4*)(Xs + PLANE + tq * ROW + kb * 2) = v;
        v.x = (unsigned)sh_[0] | ((unsigned)sh_[1] << 16);
        v.y = (unsigned)sh_[2] | ((unsigned)sh_[3] << 16);
        v.z = (unsigned)sh_[4] | ((unsigned)sh_[5] << 16);
        v.w = (unsigned)sh_[6] | ((unsigned)sh_[7] << 16);
        *(uint4*)(Xs + tq * ROW + (128 + kb) * 2) = v;
        v.x = (unsigned)sl_[0] | ((unsigned)sl_[1] << 16);
        v.y = (unsigned)sl_[2] | ((unsigned)sl_[3] << 16);
        v.z = (unsigned)sl_[4] | ((unsigned)sl_[5] << 16);
        v.w = (unsigned)sl_[6] | ((unsigned)sl_[7] << 16);
        *(uint4*)(Xs + PLANE + tq * ROW + (128 + kb) * 2) = v;
      }
    }
  }
  __syncthreads();

  const int w = t >> 6, lane = t & 63;
  const int quad = lane >> 4, ml = lane & 15;
  const unsigned int bvoff = (unsigned int)lane * 16u;

#pragma unroll
  for (int layer = 0; layer < 2; ++layer) {
    const unsigned short* wb = wmlp + layer * 131072;
    f4v acc[2][4];
#pragma unroll
    for (int i = 0; i < 2; ++i)
#pragma unroll
      for (int j = 0; j < 4; ++j) acc[i][j] = (f4v){0.0f, 0.0f, 0.0f, 0.0f};
#pragma unroll
    for (int kstep = 0; kstep < 8; ++kstep) {
      s8v Bh[4], Bl[4];
#pragma unroll
      for (int j = 0; j < 4; ++j) {
        unsigned int off = (unsigned int)((w * 4 + j) * 8 + kstep) * 1024u + bvoff;
        Bh[j] = *(const s8v*)((const char*)wb + off);
        Bl[j] = *(const s8v*)((const char*)(wb + 65536) + off);
      }
#pragma unroll
      for (int i = 0; i < 2; ++i) {
        const int aoff = (i * 16 + ml) * ROW + (kstep * 32 + quad * 8) * 2;
        s8v Ah = *(const s8v*)(Xs + aoff);
        s8v Al = *(const s8v*)(Xs + PLANE + aoff);
#pragma unroll
        for (int j = 0; j < 4; ++j) {
          acc[i][j] = __builtin_amdgcn_mfma_f32_16x16x32_bf16(Ah, Bh[j], acc[i][j], 0, 0, 0);
          acc[i][j] = __builtin_amdgcn_mfma_f32_16x16x32_bf16(Al, Bh[j], acc[i][j], 0, 0, 0);
          acc[i][j] = __builtin_amdgcn_mfma_f32_16x16x32_bf16(Ah, Bl[j], acc[i][j], 0, 0, 0);
        }
      }
    }
    __syncthreads();
    const float* bs = layer ? b2 : b1;
    float bj[4];
#pragma unroll
    for (int j = 0; j < 4; ++j) bj[j] = bs[w * 64 + j * 16 + ml];
    if (layer == 0) {
#pragma unroll
      for (int i = 0; i < 2; ++i)
#pragma unroll
        for (int j = 0; j < 4; ++j)
#pragma unroll
          for (int reg = 0; reg < 4; ++reg) {
            int m = i * 16 + quad * 4 + reg;
            int n = w * 64 + j * 16 + ml;
            float v = fmaxf(acc[i][j][reg] + bj[j], 0.0f);
            unsigned short hi = f2bf(v);
            unsigned short lo = f2bf(v - bf2f(hi));
            *(unsigned short*)(Xs + m * ROW + n * 2) = hi;
            *(unsigned short*)(Xs + PLANE + m * ROW + n * 2) = lo;
          }
    } else {
      // fp32 X rows [32][264] (fills the 33,792 B union exactly)
#pragma unroll
      for (int i = 0; i < 2; ++i)
#pragma unroll
        for (int j = 0; j < 4; ++j)
#pragma unroll
          for (int reg = 0; reg < 4; ++reg) {
            int m = i * 16 + quad * 4 + reg;
            int n = w * 64 + j * 16 + ml;
            float v = fmaxf(acc[i][j][reg] + bj[j], 0.0f);
            *(float*)(Xs + ((size_t)m * 264 + n) * 4) = v;
          }
    }
    __syncthreads();
  }

  // ---- phase 3: 3-wide output layer (8 threads per query) ----
  {
    const int tq = t >> 3, ts = t & 7;
    const float* xr = (const float*)(Xs + (size_t)tq * 264 * 4);
    float c0 = 0, c1 = 0, c2 = 0;
    for (int k = ts * 32; k < ts * 32 + 32; ++k) {
      float xv = xr[k];
      c0 += xv * w3[k];
      c1 += xv * w3[256 + k];
      c2 += xv * w3[512 + k];
    }
    c0 += __shfl_down(c0, 4, 8); c0 += __shfl_down(c0, 2, 8); c0 += __shfl_down(c0, 1, 8);
    c1 += __shfl_down(c1, 4, 8); c1 += __shfl_down(c1, 2, 8); c1 += __shfl_down(c1, 1, 8);
    c2 += __shfl_down(c2, 4, 8); c2 += __shfl_down(c2, 2, 8); c2 += __shfl_down(c2, 1, 8);
    if (ts == 0) {
      const int qg = q0 + tq;
      float* o = out + (size_t)qg * 3;
      o[0] = c0 + b3[0];
      o[1] = c1 + b3[1];
      o[2] = c2 + b3[2];
    }
  }
}

// ---------------- launch ----------------
extern "C" void kernel_launch(void* const* d_in, const int* in_sizes, int n_in,
                              void* d_out, int out_size, void* d_ws, size_t ws_size,
                              hipStream_t stream) {
  (void)in_sizes; (void)n_in; (void)out_size; (void)ws_size;
  const float* feat   = (const float*)d_in[0];
  const float* coord  = (const float*)d_in[1];
  const float* cell   = (const float*)d_in[2];
  const float* cls_w1 = (const float*)d_in[3];
  const float* cls_b1 = (const float*)d_in[4];
  const float* cls_w2 = (const float*)d_in[5];
  const float* cls_b2 = (const float*)d_in[6];
  const float* sigx   = (const float*)d_in[7];
  const float* sigy   = (const float*)d_in[8];
  const float* opac   = (const float*)d_in[9];
  const float* rho    = (const float*)d_in[10];
  const float* coef_w = (const float*)d_in[11];
  const float* coef_b = (const float*)d_in[12];
  const float* freq_w = (const float*)d_in[13];
  const float* freq_b = (const float*)d_in[14];
  const float* phw    = (const float*)d_in[15];
  const float* w1     = (const float*)d_in[16];
  const float* b1     = (const float*)d_in[17];
  const float* w2     = (const float*)d_in[18];
  const float* b2     = (const float*)d_in[19];
  const float* w3     = (const float*)d_in[20];
  const float* b3     = (const float*)d_in[21];

  char* ws = (char*)d_ws;
  unsigned short* fbh = (unsigned short*)(ws + OFF_FBH);
  unsigned short* fbl = (unsigned short*)(ws + OFF_FBL);
  unsigned short* gfh = (unsigned short*)(ws + OFF_GFH);   // overlap fb (dead after conv1)
  unsigned short* gfl = (unsigned short*)(ws + OFF_GFL);
  float* h_buf = (float*)(ws + OFF_H);
  unsigned short* cfb = (unsigned short*)(ws + OFF_CF);    // fp16
  unsigned short* wph = (unsigned short*)(ws + OFF_WPH);
  unsigned short* wpl = (unsigned short*)(ws + OFF_WPL);
  unsigned short* w1h = (unsigned short*)(ws + OFF_W1H);
  unsigned short* w1l = (unsigned short*)(ws + OFF_W1L);
  unsigned short* wmlp = (unsigned short*)(ws + OFF_WMLP);
  float* wsums = (float*)(ws + OFF_WSUM);
  float* wk    = (float*)(ws + OFF_WK);
  float* outp  = (float*)d_out;

  hipLaunchKernelGGL(k_init, dim3(1), dim3(256), 0, stream, wsums);
  hipLaunchKernelGGL(k_prepw, dim3(1152), dim3(256), 0, stream, coef_w, freq_w, wph, wpl);
  hipLaunchKernelGGL(k_prepw1, dim3(144), dim3(256), 0, stream, cls_w1, w1h, w1l);
  hipLaunchKernelGGL(k_prepmlp, dim3(512), dim3(256), 0, stream, w1, w2, wmlp);
  hipLaunchKernelGGL(k_prepfeat, dim3(784), dim3(256), 0, stream, feat, fbh, fbl);
  hipLaunchKernelGGL(k_conv1_mfma, dim3(392), dim3(256), 0, stream,
                     fbh, fbl, w1h, w1l, cls_b1, h_buf);
  hipLaunchKernelGGL(k_wavg, dim3(196), dim3(256), 0, stream,
                     h_buf, cls_w2, cls_b2, sigx, sigy, opac, rho, wsums);
  hipLaunchKernelGGL(k_finalize, dim3(1), dim3(256), 0, stream, wsums, wk);

  for (int b = 0; b < kB; ++b) {
    const float* feat_b = feat + (size_t)b * 64 * kH1 * kH1;
    hipLaunchKernelGGL(k_splat, dim3(256), dim3(256), 0, stream, feat_b, wk, gfh, gfl);
    hipLaunchKernelGGL(k_conv2_mfma, dim3(784), dim3(256), 0, stream,
                       gfh, gfl, wph, wpl, coef_b, freq_b, cfb);
    hipLaunchKernelGGL(k_query_mfma, dim3(1568), dim3(256), 0, stream,
                       cfb, coord, cell, phw, wmlp, b1, b2, w3, b3, outp, b * kQ);
  }
}

// Round 13
// 884.949 us; speedup vs baseline: 1.2453x; 1.1982x over previous
//
#include <hip/hip_runtime.h>
#include <hip/hip_fp16.h>
#include <math.h>

// ---------------- problem constants ----------------
namespace {
constexpr int kB   = 4;
constexpr int kNG  = 100;
constexpr int kH1  = 112;            // feat H/W
constexpr int kH2  = 224;            // upscaled H/W
constexpr int kQ   = kH2 * kH2;      // 50176 queries per batch image
constexpr int kP1  = kH1 * kH1;      // 12544 pixels per image (feat res)

// ---- path B (per-image loop) workspace layout, ~79 MB (proven fits) ----
constexpr size_t B_FBH  = 0;
constexpr size_t B_FBL  = 6422528;
constexpr size_t B_GFH  = 0;                  // overlaps fb (dead after conv1)
constexpr size_t B_GFL  = 6422528;
constexpr size_t B_H    = 12845056;
constexpr size_t B_CF   = 25690112;           // fp16 cf, ONE image (51.4 MB)
constexpr size_t B_WBASE= B_CF + 51380224;

// ---- path A (batched) workspace layout, ~259 MB ----
constexpr size_t A_FBH  = 0;
constexpr size_t A_FBL  = 6422528;
constexpr size_t A_H    = 12845056;           // dead after wavg
constexpr size_t A_GFH  = 0;                  // 4-image gfeat hi (25.7 MB), after fb/h dead
constexpr size_t A_GFL  = 25690112;
constexpr size_t A_CF   = 51380224;           // 4-image fp16 cf (205.5 MB)
constexpr size_t A_WBASE= A_CF + 205520896;   // = 256,901,120
constexpr size_t A_TOTAL= A_WBASE + 1893376;  // ~258.8 MB

// weight region offsets (relative to WBASE, shared by both paths)
constexpr size_t W_WPH  = 0;
constexpr size_t W_WPL  = 589824;
constexpr size_t W_W1H  = 1179648;
constexpr size_t W_W1L  = 1253376;
constexpr size_t W_WMLP = 1327104;
constexpr size_t W_WSUM = 1851392;
constexpr size_t W_WK   = 1852416;
}  // namespace

using s8v = __attribute__((ext_vector_type(8))) short;   // 8 bf16 (4 VGPRs)
using f4v = __attribute__((ext_vector_type(4))) float;   // MFMA acc
using u4v = __attribute__((ext_vector_type(4))) unsigned int;  // native vec for nt-store

__device__ __forceinline__ unsigned short f2bf(float f) {
  unsigned int u = __float_as_uint(f);
  unsigned int r = u + 0x7fffu + ((u >> 16) & 1u);   // round-nearest-even
  return (unsigned short)(r >> 16);
}
__device__ __forceinline__ float bf2f(unsigned short h) {
  return __uint_as_float((unsigned int)h << 16);
}
__device__ __forceinline__ unsigned short f2h(float f) {
  return __builtin_bit_cast(unsigned short, __float2half(f));  // RNE
}
__device__ __forceinline__ float h2f(unsigned short u) {
  return __half2float(__builtin_bit_cast(__half, u));
}

// ---------------- tiny helpers ----------------
__global__ void k_init(float* wsums) {
  int t = threadIdx.x;
  if (t < 196) wsums[t] = 0.0f;
}

// feat fp32 channel-major -> pixel-major bf16 hi/lo
__global__ __launch_bounds__(256) void k_prepfeat(const float* __restrict__ feat,
                                                  unsigned short* __restrict__ fbh,
                                                  unsigned short* __restrict__ fbl) {
  __shared__ float ls[64 * 65];
  const int t = threadIdx.x;
  const int b = blockIdx.x / 196;
  const int seg = blockIdx.x % 196;
  const int pixbase = seg * 64;
  for (int idx = t; idx < 4096; idx += 256) {
    int ci = idx >> 6, px = idx & 63;
    ls[px * 65 + ci] = feat[((size_t)(b * 64 + ci)) * kP1 + pixbase + px];
  }
  __syncthreads();
  for (int idx = t; idx < 4096; idx += 256) {
    int px = idx >> 6, ci = idx & 63;
    float v = ls[px * 65 + ci];
    unsigned short hi = f2bf(v);
    unsigned short lo = f2bf(v - bf2f(hi));
    size_t o = ((size_t)(b * kP1 + pixbase + px)) * 64 + ci;
    fbh[o] = hi;
    fbl[o] = lo;
  }
}

// Pack conv2 weights into MFMA B-fragment order, split bf16 hi/lo.
__global__ void k_prepw(const float* __restrict__ cw, const float* __restrict__ fw,
                        unsigned short* __restrict__ wph, unsigned short* __restrict__ wpl) {
  int e = blockIdx.x * 256 + threadIdx.x;   // 512*576 = 294912
  int co = e / 576, k = e % 576;
  int ci = k & 63, kk = k >> 6;
  float v = (co < 256) ? cw[co * 576 + ci * 9 + kk] : fw[(co - 256) * 576 + ci * 9 + kk];
  unsigned short hi = f2bf(v);
  unsigned short lo = f2bf(v - bf2f(hi));
  int n16 = co >> 4, nl = co & 15;
  int kstep = k >> 5, kr = k & 31;
  int dst = ((n16 * 18 + kstep) * 64 + (kr >> 3) * 16 + nl) * 8 + (kr & 7);
  wph[dst] = hi;
  wpl[dst] = lo;
}

// Pack conv1 weights (64 co) into the same B-frag order.
__global__ void k_prepw1(const float* __restrict__ w1src,
                         unsigned short* __restrict__ wph, unsigned short* __restrict__ wpl) {
  int e = blockIdx.x * 256 + threadIdx.x;   // 64*576 = 36864
  int co = e / 576, k = e % 576;
  int ci = k & 63, kk = k >> 6;
  float v = w1src[co * 576 + ci * 9 + kk];
  unsigned short hi = f2bf(v);
  unsigned short lo = f2bf(v - bf2f(hi));
  int n16 = co >> 4, nl = co & 15;
  int kstep = k >> 5, kr = k & 31;
  int dst = ((n16 * 18 + kstep) * 64 + (kr >> 3) * 16 + nl) * 8 + (kr & 7);
  wph[dst] = hi;
  wpl[dst] = lo;
}

// Pack MLP W1/W2 into B-frag order hi/lo. wmlp layout: [mat][hi/lo][65536 bf16]
__global__ void k_prepmlp(const float* __restrict__ w1, const float* __restrict__ w2,
                          unsigned short* __restrict__ wp) {
  int e = blockIdx.x * 256 + threadIdx.x;   // 131072
  int mat = e >> 16, idx = e & 65535;
  int j = idx >> 8, k = idx & 255;
  float v = (mat ? w2 : w1)[j * 256 + k];
  unsigned short hi = f2bf(v);
  unsigned short lo = f2bf(v - bf2f(hi));
  int n16 = j >> 4, nl = j & 15;
  int kstep = k >> 5, kr = k & 31;
  int dst = ((n16 * 8 + kstep) * 64 + (kr >> 3) * 16 + nl) * 8 + (kr & 7);
  wp[mat * 131072 + dst] = hi;
  wp[mat * 131072 + 65536 + dst] = lo;
}

// ---------------- conv1 as bf16x3 MFMA implicit GEMM, ReLU, pixel-major fp32 out ----------------
__global__ __launch_bounds__(256) void k_conv1_mfma(
    const unsigned short* __restrict__ fbh, const unsigned short* __restrict__ fbl,
    const unsigned short* __restrict__ wph, const unsigned short* __restrict__ wpl,
    const float* __restrict__ bias, float* __restrict__ outp) {  // h [4*12544][64]
  __shared__ __attribute__((aligned(16))) char Asb[2 * 180 * 144];  // 51,840 B
  const int t = threadIdx.x;
  const int blk = blockIdx.x;          // 4 b * 7 ty * 14 tx = 392
  const int b = blk / 98;
  const int mt = blk % 98;
  const int ty = mt / 14, tx = mt % 14;
  const int py0 = ty * 16, px0 = tx * 8;

  for (int idx = t; idx < 2880; idx += 256) {
    int plane = idx >= 1440;
    int r2 = plane ? idx - 1440 : idx;
    int p = r2 >> 3, c8 = r2 & 7;
    int pr = p / 10, pc = p % 10;
    int gy = py0 - 1 + pr, gx = px0 - 1 + pc;
    uint4 u = make_uint4(0u, 0u, 0u, 0u);
    if (gy >= 0 && gy < kH1 && gx >= 0 && gx < kH1) {
      const unsigned short* src = (plane ? fbl : fbh) +
          ((size_t)(b * kP1 + gy * kH1 + gx)) * 64 + c8 * 8;
      u = *(const uint4*)src;
    }
    *(uint4*)(Asb + plane * 25920 + p * 144 + c8 * 16) = u;
  }
  __syncthreads();

  const int w = t >> 6, lane = t & 63;
  const int quad = lane >> 4, ml = lane & 15;

  f4v acc[8];
#pragma unroll
  for (int i = 0; i < 8; ++i) acc[i] = (f4v){0.0f, 0.0f, 0.0f, 0.0f};

  const unsigned int bvoff = (unsigned int)lane * 16u;
#pragma unroll
  for (int kk = 0; kk < 9; ++kk) {
    const int ky = kk / 3, kx = kk % 3;
#pragma unroll
    for (int cs = 0; cs < 2; ++cs) {
      const int kstep = kk * 2 + cs;
      unsigned int off = ((unsigned int)(w * 18 + kstep)) * 1024u + bvoff;
      s8v Bh = *(const s8v*)((const char*)wph + off);
      s8v Bl = *(const s8v*)((const char*)wpl + off);
#pragma unroll
      for (int i = 0; i < 8; ++i) {
        const int aoff = ((2 * i + (ml >> 3) + ky) * 10 + (ml & 7) + kx) * 144 + cs * 64 + quad * 16;
        s8v Ah = *(const s8v*)(Asb + aoff);
        s8v Al = *(const s8v*)(Asb + 25920 + aoff);
        acc[i] = __builtin_amdgcn_mfma_f32_16x16x32_bf16(Ah, Bh, acc[i], 0, 0, 0);
        acc[i] = __builtin_amdgcn_mfma_f32_16x16x32_bf16(Al, Bh, acc[i], 0, 0, 0);
        acc[i] = __builtin_amdgcn_mfma_f32_16x16x32_bf16(Ah, Bl, acc[i], 0, 0, 0);
      }
    }
  }

  const float bv = bias[w * 16 + ml];
#pragma unroll
  for (int i = 0; i < 8; ++i)
#pragma unroll
    for (int reg = 0; reg < 4; ++reg) {
      int m = i * 16 + quad * 4 + reg;
      int Y = py0 + (m >> 3), X = px0 + (m & 7);
      outp[((size_t)(b * kP1 + Y * kH1 + X)) * 64 + w * 16 + ml] =
          fmaxf(acc[i][reg] + bv, 0.0f);
    }
}

// ---------------- 1x1 conv + softmax + weighted sums -> wsums[4][49] ----------------
__global__ __launch_bounds__(256) void k_wavg(
    const float* __restrict__ h, const float* __restrict__ w2, const float* __restrict__ b2,
    const float* __restrict__ sx, const float* __restrict__ sy,
    const float* __restrict__ op, const float* __restrict__ rho,
    float* __restrict__ wsums) {
  __shared__ float w2s[kNG * 64];
  __shared__ float prm[4 * kNG];
  __shared__ float b2s[kNG];
  __shared__ float pl[196];
  const int t = threadIdx.x;
  for (int i = t; i < kNG * 64; i += 256) w2s[i] = w2[i];
  if (t < kNG) {
    prm[t] = sx[t];
    prm[kNG + t] = sy[t];
    prm[2 * kNG + t] = op[t];
    prm[3 * kNG + t] = rho[t];
    b2s[t] = b2[t];
  }
  if (t < 196) pl[t] = 0.0f;
  __syncthreads();
  const int id = blockIdx.x * 256 + t;
  float hreg[64];
  const float4* hp = (const float4*)(h + (size_t)id * 64);
#pragma unroll
  for (int i = 0; i < 16; ++i) {
    float4 v = hp[i];
    hreg[4 * i] = v.x; hreg[4 * i + 1] = v.y;
    hreg[4 * i + 2] = v.z; hreg[4 * i + 3] = v.w;
  }
  float S = 0, Sx = 0, Sy = 0, So = 0, Sr = 0;
  for (int g = 0; g < kNG; ++g) {
    float d = b2s[g];
    const float4* wp = (const float4*)(w2s + g * 64);
#pragma unroll
    for (int i = 0; i < 16; ++i) {
      float4 w = wp[i];
      d += hreg[4 * i] * w.x + hreg[4 * i + 1] * w.y +
           hreg[4 * i + 2] * w.z + hreg[4 * i + 3] * w.w;
    }
    float e = expf(d);
    S += e;
    Sx += e * prm[g];
    Sy += e * prm[kNG + g];
    So += e * prm[2 * kNG + g];
    Sr += e * prm[3 * kNG + g];
  }
  const int rem = id % (kH1 * kH1);
  const int p = ((rem / kH1) % 7) * 7 + ((rem % kH1) % 7);
  const float inv = 1.0f / S;
  atomicAdd(&pl[p], Sx * inv);
  atomicAdd(&pl[49 + p], Sy * inv);
  atomicAdd(&pl[98 + p], So * inv);
  atomicAdd(&pl[147 + p], Sr * inv);
  __syncthreads();
  if (t < 196) atomicAdd(&wsums[t], pl[t]);
}

// ---------------- build wk[p][h][w] ----------------
__global__ __launch_bounds__(256) void k_finalize(const float* __restrict__ wsums,
                                                  float* __restrict__ wk) {
  __shared__ float kern_s[49 * 25];
  __shared__ float wavg_s[196];
  const int t = threadIdx.x;
  if (t < 196) wavg_s[t] = wsums[t] * (1.0f / 1024.0f);
  __syncthreads();
  if (t < 49) {
    float wsx = wavg_s[t], wsy = wavg_s[49 + t], wr = wavg_s[147 + t];
    float c00 = wsx * wsx + 1e-5f;
    float c11 = wsy * wsy + 1e-5f;
    float c01 = wr * wsx * wsy;
    float det = c00 * c11 - c01 * c01;
    float i00 = c11 / det, i11 = c00 / det, i01 = -c01 / det;
    float nrm = 1.0f / (2.0f * 3.14159265358979323846f * sqrtf(det));
    float vals[25];
    float mx = -1e30f;
#pragma unroll
    for (int i = 0; i < 5; ++i) {
#pragma unroll
      for (int j = 0; j < 5; ++j) {
        float yv = -5.0f + 2.5f * (float)i;
        float xv = -5.0f + 2.5f * (float)j;
        float z = -0.5f * (i00 * xv * xv + 2.0f * i01 * xv * yv + i11 * yv * yv);
        float v = expf(z) * nrm;
        vals[i * 5 + j] = v;
        mx = fmaxf(mx, v);
      }
    }
#pragma unroll
    for (int k = 0; k < 25; ++k) kern_s[t * 25 + k] = vals[k] / mx;
  }
  __syncthreads();
  for (int idx = t; idx < 49 * 196; idx += 256) {
    const int p = idx / 196;
    const int hw = idx % 196;
    const int hh = hw / 14, ww = hw % 14;
    float txv = (0.5f - (float)(p / 7) / 7.0f) * 2.0f;
    float tyv = (0.5f - (float)(p % 7) / 7.0f) * 2.0f;
    float gxv = (-1.0f + (float)ww * (2.0f / 13.0f)) + txv;
    float gyv = (-1.0f + (float)hh * (2.0f / 13.0f)) + tyv;
    float pxv = (gxv + 1.0f) * 0.5f * 13.0f;
    float pyv = (gyv + 1.0f) * 0.5f * 13.0f;
    float x0f = floorf(pxv), y0f = floorf(pyv);
    int x0 = (int)x0f, y0 = (int)y0f;
    float wx = pxv - x0f, wy = pyv - y0f;
    auto samp = [&](int yi, int xi) -> float {
      if (yi < 4 || yi >= 9 || xi < 4 || xi >= 9) return 0.0f;
      return kern_s[p * 25 + (yi - 4) * 5 + (xi - 4)];
    };
    float kt = samp(y0, x0) * (1.0f - wy) * (1.0f - wx) +
               samp(y0, x0 + 1) * (1.0f - wy) * wx +
               samp(y0 + 1, x0) * wy * (1.0f - wx) +
               samp(y0 + 1, x0 + 1) * wy * wx;
    wk[idx] = wavg_s[98 + p] * kt;
  }
}

// ---------------- splat -> pixel-major bf16 hi/lo gfeat (batch-decoded) ----------------
// grid = NB*256; b = blockIdx>>8 (grid 256 -> b=0, per-image pointers).
__global__ __launch_bounds__(256) void k_splat(const float* __restrict__ feat,
                                               const float* __restrict__ wk,
                                               unsigned short* __restrict__ gfh,
                                               unsigned short* __restrict__ gfl) {
  __shared__ float fs[64 * 49];
  __shared__ float wks[49 * 196];
  const int t = threadIdx.x;
  const int b = blockIdx.x >> 8;
  const int rem = blockIdx.x & 255;
  const int ry = rem >> 4, rx = rem & 15;
  const float* featb = feat + (size_t)b * 64 * kP1;
  for (int idx = t; idx < 64 * 49; idx += 256) {
    int ci = idx / 49, p = idx % 49;
    int gy = ry * 7 + p / 7, gx = rx * 7 + p % 7;
    fs[idx] = featb[((size_t)ci * kH1 + gy) * kH1 + gx];
  }
  for (int idx = t; idx < 49 * 196; idx += 256) wks[idx] = wk[idx];
  __syncthreads();
  const int ci = t & 63;
  const int s = t >> 6;
  const int h0 = (s >> 1) * 7, w0 = (s & 1) * 7;
  float acc[49];
#pragma unroll
  for (int i = 0; i < 49; ++i) acc[i] = 0.0f;
  for (int p = 0; p < 49; ++p) {
    float f = fs[ci * 49 + p];
#pragma unroll
    for (int i = 0; i < 7; ++i)
#pragma unroll
      for (int j = 0; j < 7; ++j)
        acc[i * 7 + j] += f * wks[p * 196 + (h0 + i) * 14 + (w0 + j)];
  }
#pragma unroll
  for (int i = 0; i < 7; ++i)
#pragma unroll
    for (int j = 0; j < 7; ++j) {
      int Y = ry * 14 + h0 + i;
      int X = rx * 14 + w0 + j;
      float v = fminf(fmaxf(acc[i * 7 + j], 0.0f), 1.0f);
      unsigned short hi = f2bf(v);
      unsigned short lo = f2bf(v - bf2f(hi));
      size_t o = ((size_t)(b * kQ + Y * kH2 + X)) * 64 + ci;
      gfh[o] = hi;
      gfl[o] = lo;
    }
}

// ---------------- conv2 as bf16x3 MFMA implicit GEMM, fp16 output (batch-decoded) ----------------
// grid = NB*784; b = blockIdx/784 (grid 784 -> b=0, per-image pointers).
// Free VGPR alloc (no min-waves clause: r9 spill lesson); M=128 tile (r11: M=64 doubled traffic).
__global__ __launch_bounds__(256) void k_conv2_mfma(
    const unsigned short* __restrict__ gfh, const unsigned short* __restrict__ gfl,
    const unsigned short* __restrict__ wph, const unsigned short* __restrict__ wpl,
    const float* __restrict__ coef_b, const float* __restrict__ freq_b,
    unsigned short* __restrict__ outp) {     // fp16 [NB*224*224][512]
  __shared__ __attribute__((aligned(16))) char Asb[2 * 180 * 144];  // 51,840 B
  const int t = threadIdx.x;
  const int b = blockIdx.x / 784;
  const int blk = blockIdx.x % 784;
  const int nb = blk & 1;
  const int mt = blk >> 1;
  const int ty = mt / 28, tx = mt % 28;
  const int py0 = ty * 16, px0 = tx * 8;

  for (int idx = t; idx < 2880; idx += 256) {
    int plane = idx >= 1440;
    int r2 = plane ? idx - 1440 : idx;
    int p = r2 >> 3, c8 = r2 & 7;
    int pr = p / 10, pc = p % 10;
    int gy = py0 - 1 + pr, gx = px0 - 1 + pc;
    uint4 u = make_uint4(0u, 0u, 0u, 0u);
    if (gy >= 0 && gy < kH2 && gx >= 0 && gx < kH2) {
      const unsigned short* src = (plane ? gfl : gfh) +
          ((size_t)(b * kQ + gy * kH2 + gx)) * 64 + c8 * 8;
      u = *(const uint4*)src;
    }
    *(uint4*)(Asb + plane * 25920 + p * 144 + c8 * 16) = u;
  }
  __syncthreads();

  const int w = t >> 6, lane = t & 63;
  const int quad = lane >> 4, ml = lane & 15;
  const int abase = (((ml >> 3) * 10) + (ml & 7)) * 144 + quad * 16;
  const int n16base = nb * 16 + w * 4;
  const unsigned int bvoff = (unsigned int)lane * 16u;

  f4v acc[8][4];
#pragma unroll
  for (int i = 0; i < 8; ++i)
#pragma unroll
    for (int j = 0; j < 4; ++j) acc[i][j] = (f4v){0.0f, 0.0f, 0.0f, 0.0f};

#pragma unroll
  for (int kk = 0; kk < 9; ++kk) {
    const int ky = kk / 3, kx = kk % 3;
#pragma unroll
    for (int cs = 0; cs < 2; ++cs) {
      const int kstep = kk * 2 + cs;
      s8v Bh[4], Bl[4];
#pragma unroll
      for (int j = 0; j < 4; ++j) {
        unsigned int off = ((unsigned int)(n16base + j) * 18u + (unsigned int)kstep) * 1024u + bvoff;
        Bh[j] = *(const s8v*)((const char*)wph + off);
        Bl[j] = *(const s8v*)((const char*)wpl + off);
      }
#pragma unroll
      for (int i = 0; i < 8; ++i) {
        const int aoff = ((2 * i + ky) * 10 + kx) * 144 + cs * 64 + abase;
        s8v Ah = *(const s8v*)(Asb + aoff);
        s8v Al = *(const s8v*)(Asb + 25920 + aoff);
#pragma unroll
        for (int j = 0; j < 4; ++j) {
          acc[i][j] = __builtin_amdgcn_mfma_f32_16x16x32_bf16(Ah, Bh[j], acc[i][j], 0, 0, 0);
          acc[i][j] = __builtin_amdgcn_mfma_f32_16x16x32_bf16(Al, Bh[j], acc[i][j], 0, 0, 0);
          acc[i][j] = __builtin_amdgcn_mfma_f32_16x16x32_bf16(Ah, Bl[j], acc[i][j], 0, 0, 0);
        }
      }
    }
  }

  // ---- epilogue via LDS, convert to fp16, nontemporal full-line stores ----
  const int cobase = nb * 256 + w * 64;
  float bj[4];
#pragma unroll
  for (int j = 0; j < 4; ++j) {
    int co = cobase + j * 16 + ml;
    bj[j] = (co < 256) ? coef_b[co] : freq_b[co - 256];
  }
  __syncthreads();               // Asb (A-tile) dead; reuse as staging
  float* Ls = (float*)Asb;       // [32 pixels][268 floats]
  const int pq = t >> 3;
  const int ts = t & 7;
#pragma unroll
  for (int c = 0; c < 4; ++c) {
#pragma unroll
    for (int ii = 0; ii < 2; ++ii) {
      const int i = c * 2 + ii;
#pragma unroll
      for (int j = 0; j < 4; ++j)
#pragma unroll
        for (int reg = 0; reg < 4; ++reg) {
          const int p = ii * 16 + quad * 4 + reg;           // 0..31
          Ls[p * 268 + w * 64 + j * 16 + ml] = acc[i][j][reg] + bj[j];
        }
    }
    __syncthreads();
    const int m = c * 32 + pq;                              // pixel in M-tile
    const int Y = py0 + (m >> 3), X = px0 + (m & 7);
    unsigned short* orow = outp + ((size_t)(b * kQ + Y * kH2 + X)) * 512 + nb * 256;
    const float* lrow = Ls + pq * 268;
#pragma unroll
    for (int u = 0; u < 4; ++u) {
      float4 a = *(const float4*)(lrow + u * 64 + ts * 8);
      float4 bb = *(const float4*)(lrow + u * 64 + ts * 8 + 4);
      u4v v;
      v.x = (unsigned)f2h(a.x) | ((unsigned)f2h(a.y) << 16);
      v.y = (unsigned)f2h(a.z) | ((unsigned)f2h(a.w) << 16);
      v.z = (unsigned)f2h(bb.x) | ((unsigned)f2h(bb.y) << 16);
      v.w = (unsigned)f2h(bb.z) | ((unsigned)f2h(bb.w) << 16);
      __builtin_nontemporal_store(v, (u4v*)(orow + u * 64 + ts * 8));
    }
    __syncthreads();
  }
}

// ---------------- fused query: fp16 gather + basis + bf16x3 MFMA MLP (batch-decoded) ----------------
// 32-query blocks (r12: 4 blocks/CU). qg = q_base + blockIdx*32 + tq; image b = qg/kQ;
// cf plane = cfh + b*cf_stride. Path A: q_base=0, stride=kQ*512. Path B: q_base=b*kQ, stride=0.
__global__ __launch_bounds__(256) void k_query_mfma(
    const unsigned short* __restrict__ cfh,
    const float* __restrict__ coord,
    const float* __restrict__ cell, const float* __restrict__ phw,
    const unsigned short* __restrict__ wmlp,   // [2][hi/lo][65536]
    const float* __restrict__ b1, const float* __restrict__ b2,
    const float* __restrict__ w3, const float* __restrict__ b3,
    float* __restrict__ out, int q_base, size_t cf_stride) {
  __shared__ __attribute__((aligned(16))) char Xs[2 * 32 * 264 * 2];  // 33,792 B
  constexpr int ROW = 264 * 2;
  constexpr int PLANE = 32 * 264 * 2;
  const int t = threadIdx.x;

  // ---- phase 1: gather + basis (8 threads per query, 32 queries) ----
  {
    const int tq = t >> 3, ts = t & 7;
    const int qg = q_base + blockIdx.x * 32 + tq;
    const int b = qg / kQ;
    float gy = coord[(size_t)qg * 2 + 0];
    float gx = coord[(size_t)qg * 2 + 1];
    float fx = ((gx + 1.0f) * 224.0f - 1.0f) * 0.5f;
    float fy = ((gy + 1.0f) * 224.0f - 1.0f) * 0.5f;
    int ix = (int)rintf(fx);
    int iy = (int)rintf(fy);
    bool ok = (ix >= 0) && (ix < 224) && (iy >= 0) && (iy < 224);
    int ixc = min(max(ix, 0), 223);
    int iyc = min(max(iy, 0), 223);
    float m = ok ? 1.0f : 0.0f;
    float qcy = ok ? (-1.0f + (1.0f / 224.0f) + (2.0f / 224.0f) * (float)iyc) : 0.0f;
    float qcx = ok ? (-1.0f + (1.0f / 224.0f) + (2.0f / 224.0f) * (float)ixc) : 0.0f;
    float rel0 = (gy - qcy) * 224.0f;
    float rel1 = (gx - qcx) * 224.0f;
    float rc0 = cell[(size_t)qg * 2 + 0] * 224.0f;
    float rc1 = cell[(size_t)qg * 2 + 1] * 224.0f;
    const unsigned short* base = cfh + (size_t)b * cf_stride +
                                 (((size_t)iyc * kH2 + ixc) * 512);
    unsigned short ch_[8], cl_[8], sh_[8], sl_[8];
#pragma unroll
    for (int u = 0; u < 4; ++u) {
      const int k4 = ts * 16 + u * 4;
      ushort4 clo = *(const ushort4*)(base + k4);
      ushort4 chi = *(const ushort4*)(base + 128 + k4);
      ushort4 f0 = *(const ushort4*)(base + 256 + 2 * k4);
      ushort4 f1 = *(const ushort4*)(base + 256 + 2 * k4 + 4);
      float fr[8] = {h2f(f0.x), h2f(f0.y), h2f(f0.z), h2f(f0.w),
                     h2f(f1.x), h2f(f1.y), h2f(f1.z), h2f(f1.w)};
      float cl4[4] = {h2f(clo.x), h2f(clo.y), h2f(clo.z), h2f(clo.w)};
      float ch4[4] = {h2f(chi.x), h2f(chi.y), h2f(chi.z), h2f(chi.w)};
#pragma unroll
      for (int e = 0; e < 4; ++e) {
        const int k = k4 + e;
        float ph = rc0 * phw[2 * k] + rc1 * phw[2 * k + 1];
        float s = m * (fr[2 * e] * rel0 + fr[2 * e + 1] * rel1) + ph;
        float sv, cv;
        sincospif(s, &sv, &cv);
        float xc = m * cl4[e] * cv;
        float xsn = m * ch4[e] * sv;
        const int sl = (u & 1) * 4 + e;
        unsigned short h1_ = f2bf(xc);
        ch_[sl] = h1_; cl_[sl] = f2bf(xc - bf2f(h1_));
        unsigned short h2_ = f2bf(xsn);
        sh_[sl] = h2_; sl_[sl] = f2bf(xsn - bf2f(h2_));
      }
      if (u & 1) {
        const int kb = ts * 16 + (u - 1) * 4;
        uint4 v;
        v.x = (unsigned)ch_[0] | ((unsigned)ch_[1] << 16);
        v.y = (unsigned)ch_[2] | ((unsigned)ch_[3] << 16);
        v.z = (unsigned)ch_[4] | ((unsigned)ch_[5] << 16);
        v.w = (unsigned)ch_[6] | ((unsigned)ch_[7] << 16);
        *(uint4*)(Xs + tq * ROW + kb * 2) = v;
        v.x = (unsigned)cl_[0] | ((unsigned)cl_[1] << 16);
        v.y = (unsigned)cl_[2] | ((unsigned)cl_[3] << 16);
        v.z = (unsigned)cl_[4] | ((unsigned)cl_[5] << 16);
        v.w = (unsigned)cl_[6] | ((unsigned)cl_[7] << 16);
        *(uint4*)(Xs + PLANE + tq * ROW + kb * 2) = v;
        v.x = (unsigned)sh_[0] | ((unsigned)sh_[1] << 16);
        v.y = (unsigned)sh_[2] | ((unsigned)sh_[3] << 16);
        v.z = (unsigned)sh_[4] | ((unsigned)sh_[5] << 16);
        v.w = (unsigned)sh_[6] | ((unsigned)sh_[7] << 16);
        *(uint4*)(Xs + tq * ROW + (128 + kb) * 2) = v;
        v.x = (unsigned)sl_[0] | ((unsigned)sl_[1] << 16);
        v.y = (unsigned)sl_[2] | ((unsigned)sl_[3] << 16);
        v.z = (unsigned)sl_[4] | ((unsigned)sl_[5] << 16);
        v.w = (unsigned)sl_[6] | ((unsigned)sl_[7] << 16);
        *(uint4*)(Xs + PLANE + tq * ROW + (128 + kb) * 2) = v;
      }
    }
  }
  __syncthreads();

  const int w = t >> 6, lane = t & 63;
  const int quad = lane >> 4, ml = lane & 15;
  const unsigned int bvoff = (unsigned int)lane * 16u;

#pragma unroll
  for (int layer = 0; layer < 2; ++layer) {
    const unsigned short* wb = wmlp + layer * 131072;
    f4v acc[2][4];
#pragma unroll
    for (int i = 0; i < 2; ++i)
#pragma unroll
      for (int j = 0; j < 4; ++j) acc[i][j] = (f4v){0.0f, 0.0f, 0.0f, 0.0f};
#pragma unroll
    for (int kstep = 0; kstep < 8; ++kstep) {
      s8v Bh[4], Bl[4];
#pragma unroll
      for (int j = 0; j < 4; ++j) {
        unsigned int off = (unsigned int)((w * 4 + j) * 8 + kstep) * 1024u + bvoff;
        Bh[j] = *(const s8v*)((const char*)wb + off);
        Bl[j] = *(const s8v*)((const char*)(wb + 65536) + off);
      }
#pragma unroll
      for (int i = 0; i < 2; ++i) {
        const int aoff = (i * 16 + ml) * ROW + (kstep * 32 + quad * 8) * 2;
        s8v Ah = *(const s8v*)(Xs + aoff);
        s8v Al = *(const s8v*)(Xs + PLANE + aoff);
#pragma unroll
        for (int j = 0; j < 4; ++j) {
          acc[i][j] = __builtin_amdgcn_mfma_f32_16x16x32_bf16(Ah, Bh[j], acc[i][j], 0, 0, 0);
          acc[i][j] = __builtin_amdgcn_mfma_f32_16x16x32_bf16(Al, Bh[j], acc[i][j], 0, 0, 0);
          acc[i][j] = __builtin_amdgcn_mfma_f32_16x16x32_bf16(Ah, Bl[j], acc[i][j], 0, 0, 0);
        }
      }
    }
    __syncthreads();
    const float* bs = layer ? b2 : b1;
    float bj[4];
#pragma unroll
    for (int j = 0; j < 4; ++j) bj[j] = bs[w * 64 + j * 16 + ml];
    if (layer == 0) {
#pragma unroll
      for (int i = 0; i < 2; ++i)
#pragma unroll
        for (int j = 0; j < 4; ++j)
#pragma unroll
          for (int reg = 0; reg < 4; ++reg) {
            int m = i * 16 + quad * 4 + reg;
            int n = w * 64 + j * 16 + ml;
            float v = fmaxf(acc[i][j][reg] + bj[j], 0.0f);
            unsigned short hi = f2bf(v);
            unsigned short lo = f2bf(v - bf2f(hi));
            *(unsigned short*)(Xs + m * ROW + n * 2) = hi;
            *(unsigned short*)(Xs + PLANE + m * ROW + n * 2) = lo;
          }
    } else {
#pragma unroll
      for (int i = 0; i < 2; ++i)
#pragma unroll
        for (int j = 0; j < 4; ++j)
#pragma unroll
          for (int reg = 0; reg < 4; ++reg) {
            int m = i * 16 + quad * 4 + reg;
            int n = w * 64 + j * 16 + ml;
            float v = fmaxf(acc[i][j][reg] + bj[j], 0.0f);
            *(float*)(Xs + ((size_t)m * 264 + n) * 4) = v;
          }
    }
    __syncthreads();
  }

  // ---- phase 3: 3-wide output layer (8 threads per query) ----
  {
    const int tq = t >> 3, ts = t & 7;
    const float* xr = (const float*)(Xs + (size_t)tq * 264 * 4);
    float c0 = 0, c1 = 0, c2 = 0;
    for (int k = ts * 32; k < ts * 32 + 32; ++k) {
      float xv = xr[k];
      c0 += xv * w3[k];
      c1 += xv * w3[256 + k];
      c2 += xv * w3[512 + k];
    }
    c0 += __shfl_down(c0, 4, 8); c0 += __shfl_down(c0, 2, 8); c0 += __shfl_down(c0, 1, 8);
    c1 += __shfl_down(c1, 4, 8); c1 += __shfl_down(c1, 2, 8); c1 += __shfl_down(c1, 1, 8);
    c2 += __shfl_down(c2, 4, 8); c2 += __shfl_down(c2, 2, 8); c2 += __shfl_down(c2, 1, 8);
    if (ts == 0) {
      const int qg = q_base + blockIdx.x * 32 + tq;
      float* o = out + (size_t)qg * 3;
      o[0] = c0 + b3[0];
      o[1] = c1 + b3[1];
      o[2] = c2 + b3[2];
    }
  }
}

// ---------------- launch ----------------
extern "C" void kernel_launch(void* const* d_in, const int* in_sizes, int n_in,
                              void* d_out, int out_size, void* d_ws, size_t ws_size,
                              hipStream_t stream) {
  (void)in_sizes; (void)n_in; (void)out_size;
  const float* feat   = (const float*)d_in[0];
  const float* coord  = (const float*)d_in[1];
  const float* cell   = (const float*)d_in[2];
  const float* cls_w1 = (const float*)d_in[3];
  const float* cls_b1 = (const float*)d_in[4];
  const float* cls_w2 = (const float*)d_in[5];
  const float* cls_b2 = (const float*)d_in[6];
  const float* sigx   = (const float*)d_in[7];
  const float* sigy   = (const float*)d_in[8];
  const float* opac   = (const float*)d_in[9];
  const float* rho    = (const float*)d_in[10];
  const float* coef_w = (const float*)d_in[11];
  const float* coef_b = (const float*)d_in[12];
  const float* freq_w = (const float*)d_in[13];
  const float* freq_b = (const float*)d_in[14];
  const float* phw    = (const float*)d_in[15];
  const float* w1     = (const float*)d_in[16];
  const float* b1     = (const float*)d_in[17];
  const float* w2     = (const float*)d_in[18];
  const float* b2     = (const float*)d_in[19];
  const float* w3     = (const float*)d_in[20];
  const float* b3     = (const float*)d_in[21];

  const bool big = ws_size >= A_TOTAL;   // path A: batched (needs 4-image cf)
  char* ws = (char*)d_ws;
  const size_t wbase = big ? A_WBASE : B_WBASE;
  unsigned short* fbh = (unsigned short*)(ws + (big ? A_FBH : B_FBH));
  unsigned short* fbl = (unsigned short*)(ws + (big ? A_FBL : B_FBL));
  unsigned short* gfh = (unsigned short*)(ws + (big ? A_GFH : B_GFH));
  unsigned short* gfl = (unsigned short*)(ws + (big ? A_GFL : B_GFL));
  float* h_buf = (float*)(ws + (big ? A_H : B_H));
  unsigned short* cfb = (unsigned short*)(ws + (big ? A_CF : B_CF));
  unsigned short* wph = (unsigned short*)(ws + wbase + W_WPH);
  unsigned short* wpl = (unsigned short*)(ws + wbase + W_WPL);
  unsigned short* w1h = (unsigned short*)(ws + wbase + W_W1H);
  unsigned short* w1l = (unsigned short*)(ws + wbase + W_W1L);
  unsigned short* wmlp = (unsigned short*)(ws + wbase + W_WMLP);
  float* wsums = (float*)(ws + wbase + W_WSUM);
  float* wk    = (float*)(ws + wbase + W_WK);
  float* outp  = (float*)d_out;

  hipLaunchKernelGGL(k_init, dim3(1), dim3(256), 0, stream, wsums);
  hipLaunchKernelGGL(k_prepw, dim3(1152), dim3(256), 0, stream, coef_w, freq_w, wph, wpl);
  hipLaunchKernelGGL(k_prepw1, dim3(144), dim3(256), 0, stream, cls_w1, w1h, w1l);
  hipLaunchKernelGGL(k_prepmlp, dim3(512), dim3(256), 0, stream, w1, w2, wmlp);
  hipLaunchKernelGGL(k_prepfeat, dim3(784), dim3(256), 0, stream, feat, fbh, fbl);
  hipLaunchKernelGGL(k_conv1_mfma, dim3(392), dim3(256), 0, stream,
                     fbh, fbl, w1h, w1l, cls_b1, h_buf);
  hipLaunchKernelGGL(k_wavg, dim3(196), dim3(256), 0, stream,
                     h_buf, cls_w2, cls_b2, sigx, sigy, opac, rho, wsums);
  hipLaunchKernelGGL(k_finalize, dim3(1), dim3(256), 0, stream, wsums, wk);

  if (big) {
    // batched: one dispatch per stage across all 4 images (kills the 1.53-round tails)
    hipLaunchKernelGGL(k_splat, dim3(4 * 256), dim3(256), 0, stream, feat, wk, gfh, gfl);
    hipLaunchKernelGGL(k_conv2_mfma, dim3(4 * 784), dim3(256), 0, stream,
                       gfh, gfl, wph, wpl, coef_b, freq_b, cfb);
    hipLaunchKernelGGL(k_query_mfma, dim3(4 * 1568), dim3(256), 0, stream,
                       cfb, coord, cell, phw, wmlp, b1, b2, w3, b3, outp,
                       0, (size_t)kQ * 512);
  } else {
    for (int b = 0; b < kB; ++b) {
      const float* feat_b = feat + (size_t)b * 64 * kP1;
      hipLaunchKernelGGL(k_splat, dim3(256), dim3(256), 0, stream, feat_b, wk, gfh, gfl);
      hipLaunchKernelGGL(k_conv2_mfma, dim3(784), dim3(256), 0, stream,
                         gfh, gfl, wph, wpl, coef_b, freq_b, cfb);
      hipLaunchKernelGGL(k_query_mfma, dim3(1568), dim3(256), 0, stream,
                         cfb, coord, cell, phw, wmlp, b1, b2, w3, b3, outp,
                         b * kQ, (size_t)0);
    }
  }
}